// Round 3
// baseline (367.220 us; speedup 1.0000x reference)
//
#include <hip/hip_runtime.h>

#define RES    28
#define DIMC   384
#define NHEAD  8
#define HDIM   48
#define DPAD   64
#define NPIX   784
#define NB     16
#define VSTR   800
#define SC2    0.20823294f    // 48^-0.5 * log2(e)
#define LOG2E  1.44269504f

typedef short bf16x8 __attribute__((ext_vector_type(8)));
typedef float f32x4  __attribute__((ext_vector_type(4)));

__device__ __forceinline__ short f2bf(float x) {
  union { float f; unsigned u; } v; v.f = x;
  return (short)((v.u + 0x7FFFu + ((v.u >> 16) & 1u)) >> 16);   // RNE
}
__device__ __forceinline__ unsigned pk_rne(float a, float b) {
  union { float f; unsigned u; } x, y; x.f = a; y.f = b;
  return __builtin_amdgcn_perm(y.u + 0x7FFFu + ((y.u >> 16) & 1u),
                               x.u + 0x7FFFu + ((x.u >> 16) & 1u), 0x07060302u);
}
__device__ __forceinline__ unsigned pk_hu(float a, float b) {   // round-half-up, 3 ops
  union { float f; unsigned u; } x, y; x.f = a; y.f = b;
  return __builtin_amdgcn_perm(y.u + 0x8000u, x.u + 0x8000u, 0x07060302u);
}
__device__ __forceinline__ float blo(unsigned u) { union { unsigned u; float f; } v; v.u = u << 16; return v.f; }
__device__ __forceinline__ float bhi(unsigned u) { union { unsigned u; float f; } v; v.u = u & 0xFFFF0000u; return v.f; }

// ================= prep: transpose+cvt X, pack W frags, bias matrix, Q/K pad zero ==========
// blocks [0,2496): transpose  [2496,2784): pack  [2784,3176): bias  [3176,3960): pads
__global__ __launch_bounds__(256) void prep_kernel(
    const float* __restrict__ ll, const float* __restrict__ ha,
    const float* __restrict__ qw, const float* __restrict__ kvw, const float* __restrict__ pw,
    const float* __restrict__ biases,
    short* __restrict__ Xll, short* __restrict__ Xha,
    short* __restrict__ Wfq, short* __restrict__ Wfkv, short* __restrict__ Wfp,
    short* __restrict__ Bt, short* __restrict__ Qb, short* __restrict__ Kb)
{
  __shared__ __align__(16) short sT[64][72];
  __shared__ float sB[NPIX];
  const int bid = blockIdx.x, t = threadIdx.x;

  if (bid < 2496) {               // ---- transpose (b,c,pix) f32 -> (b,pix,c) bf16 ----
    const int px = bid % 13, cb = (bid / 13) % 6, zz = bid / 78;
    const int which = zz >> 4, b = zz & 15;
    const float* X = (which ? ha : ll) + (size_t)b * DIMC * NPIX;
    short* T = (which ? Xha : Xll) + (size_t)b * NPIX * DIMC;
    const int c0 = cb * 64, p0 = px * 64;
    const int rrr = t >> 4, pc = (t & 15) * 4;
#pragma unroll
    for (int i = 0; i < 4; ++i) {
      const int c = rrr + 16 * i;
      if (p0 + pc < NPIX) {
        float4 v = *(const float4*)(X + (size_t)(c0 + c) * NPIX + p0 + pc);
        sT[pc + 0][c] = f2bf(v.x); sT[pc + 1][c] = f2bf(v.y);
        sT[pc + 2][c] = f2bf(v.z); sT[pc + 3][c] = f2bf(v.w);
      }
    }
    __syncthreads();
    const int pr = t >> 3, cc = (t & 7) * 8;
#pragma unroll
    for (int i = 0; i < 2; ++i) {
      const int p = pr + 32 * i;
      if (p0 + p < NPIX)
        *(bf16x8*)(T + (size_t)(p0 + p) * DIMC + c0 + cc) = *(const bf16x8*)&sT[p][cc];
    }
  } else if (bid < 2784) {        // ---- pack W -> Wf[ks][lane][mtile][8] ----
    int gid = (bid - 2496) * 256 + t;
    const float* W; short* O; int Mtot;
    if (gid < 18432)      { W = qw;  O = Wfq;  Mtot = 24; }
    else if (gid < 55296) { W = kvw; O = Wfkv; Mtot = 48; gid -= 18432; }
    else                  { W = pw;  O = Wfp;  Mtot = 24; gid -= 55296; }
    const int mtile = gid % Mtot;
    const int lk = gid / Mtot;
    const int lane = lk & 63, ks = lk >> 6;
    const int row = mtile * 16 + (lane & 15);
    const int k = ks * 32 + (lane >> 4) * 8;
    const float* src = W + (size_t)row * DIMC + k;
    const float4 a = *(const float4*)src;
    const float4 b = *(const float4*)(src + 4);
    bf16x8 o;
    o[0] = f2bf(a.x); o[1] = f2bf(a.y); o[2] = f2bf(a.z); o[3] = f2bf(a.w);
    o[4] = f2bf(b.x); o[5] = f2bf(b.y); o[6] = f2bf(b.z); o[7] = f2bf(b.w);
    *(bf16x8*)(O + (size_t)gid * 8) = o;
  } else if (bid < 3176) {        // ---- bias matrix Bt[h][n][m] = bias*log2e, bf16 ----
    const int bb = bid - 2784;
    const int h = bb / 49, mt = bb % 49;
    for (int i = t; i < NPIX; i += 256) sB[i] = biases[h * NPIX + i] * LOG2E;
    __syncthreads();
    const int mrow = mt * 16 + (t >> 4);
    const int i2 = mrow / RES, j2 = mrow - i2 * RES;
    short* orow = Bt + ((size_t)h * NPIX + mrow) * NPIX;
    for (int n0 = (t & 15) * 4; n0 < NPIX; n0 += 64) {
      float v[4];
#pragma unroll
      for (int u = 0; u < 4; ++u) {
        const int n = n0 + u;
        const int i1 = n / RES, j1 = n - i1 * RES;
        int di = i1 - i2; di = di < 0 ? -di : di;
        int dj = j1 - j2; dj = dj < 0 ? -dj : dj;
        v[u] = sB[di * RES + dj];
      }
      uint2 pk; pk.x = pk_rne(v[0], v[1]); pk.y = pk_rne(v[2], v[3]);
      *(uint2*)(orow + n0) = pk;
    }
  } else {                        // ---- zero Q/K pad cols d in [48,64) ----
    const int pp = bid - 3176;
    short* buf = (pp >= 392) ? Kb : Qb;
    const size_t r = (size_t)(pp % 392) * 256 + t;
    short* p = buf + r * DPAD + HDIM;
    *(int4*)p = make_int4(0, 0, 0, 0);
    *(int4*)(p + 8) = make_int4(0, 0, 0, 0);
  }
}

// ================= fused QKV GEMM: z=0 Q, z=1 K, z=2 V ==========
__global__ __launch_bounds__(256) void qkv_gemm(
    const short* __restrict__ Wfq, const short* __restrict__ Wfkv,
    const float* __restrict__ qb, const float* __restrict__ kvb,
    const short* __restrict__ Xll, const short* __restrict__ Xha,
    short* __restrict__ Qb, short* __restrict__ Kb, short* __restrict__ Vb)
{
  const int t = threadIdx.x;
  const int w = t >> 6, lane = t & 63;
  const int rr = lane & 15, qq = lane >> 4;
  const int z = blockIdx.z, b = blockIdx.y;
  const int pix = blockIdx.x * 16 + rr;

  const short* Wf; const float* bias; const short* Xt; int mbase, Mtot;
  if (z == 0)      { Wf = Wfq;  bias = qb;  Xt = Xll; mbase = 0;  Mtot = 24; }
  else if (z == 1) { Wf = Wfkv; bias = kvb; Xt = Xha; mbase = 0;  Mtot = 48; }
  else             { Wf = Wfkv; bias = kvb; Xt = Xha; mbase = 24; Mtot = 48; }

  const short* Xp = Xt + ((size_t)b * NPIX + pix) * DIMC + qq * 8;
  const short* wfp = Wf + ((size_t)lane * Mtot + mbase + w) * 8;
  const size_t wstep = (size_t)64 * Mtot * 8;

  f32x4 acc[6];
#pragma unroll
  for (int i = 0; i < 6; ++i) acc[i] = (f32x4){0.f, 0.f, 0.f, 0.f};

  for (int ks = 0; ks < 12; ++ks) {
    const bf16x8 xf = *(const bf16x8*)(Xp + ks * 32);
#pragma unroll
    for (int i = 0; i < 6; ++i) {
      const bf16x8 af = *(const bf16x8*)(wfp + i * 32);
      acc[i] = __builtin_amdgcn_mfma_f32_16x16x32_bf16(af, xf, acc[i], 0, 0, 0);
    }
    wfp += wstep;
  }

#pragma unroll
  for (int i = 0; i < 6; ++i) {
    const int ml = w + 4 * i;                    // local mtile
    const int chl = ml * 16 + qq * 4;            // local channel base
    const float4 bv = *(const float4*)(bias + (mbase + ml) * 16 + qq * 4);
    const float v0 = acc[i][0] + bv.x, v1 = acc[i][1] + bv.y;
    const float v2 = acc[i][2] + bv.z, v3 = acc[i][3] + bv.w;
    const int hh = chl / HDIM, d0 = chl % HDIM;
    if (z == 2) {
      short* o = Vb + (((size_t)b * NHEAD + hh) * HDIM + d0) * VSTR + pix;
      o[0] = f2bf(v0); o[VSTR] = f2bf(v1); o[2 * VSTR] = f2bf(v2); o[3 * VSTR] = f2bf(v3);
    } else {
      short* o = (z == 0 ? Qb : Kb) + (((size_t)b * NHEAD + hh) * NPIX + pix) * DPAD + d0;
      uint2 pk; pk.x = pk_rne(v0, v1); pk.y = pk_rne(v2, v3);
      *(uint2*)o = pk;
    }
  }
}

// ================= attention: one WAVE = 16 q-rows, online softmax, no barriers ==========
__global__ __launch_bounds__(256) void attn_kernel(
    const short* __restrict__ Q, const short* __restrict__ K,
    const short* __restrict__ V, const short* __restrict__ Bt,
    short* __restrict__ AO)
{
  __shared__ __align__(16) short sP[4][2][16][40];
  const int t = threadIdx.x;
  const int w = t >> 6, lane = t & 63;
  const int rr = lane & 15, qq = lane >> 4;
  const int qt = blockIdx.x * 4 + w;
  if (qt >= 49) return;
  const int h = blockIdx.y, b = blockIdx.z, bh = b * NHEAD + h;
  const int q0 = qt * 16;

  const short* Qp = Q + ((size_t)bh * NPIX + q0 + rr) * DPAD + qq * 8;
  const bf16x8 qf0 = *(const bf16x8*)Qp;
  const bf16x8 qf1 = *(const bf16x8*)(Qp + 32);

  const short* Kp = K + ((size_t)bh * NPIX + rr) * DPAD + qq * 8;
  const short* Vp = V + (size_t)bh * HDIM * VSTR + qq * 8;
  const short* Bp = Bt + ((size_t)h * NPIX + q0 + rr) * NPIX + qq * 4;

  f32x4 O[3];
#pragma unroll
  for (int i = 0; i < 3; ++i) O[i] = (f32x4){0.f, 0.f, 0.f, 0.f};
  float m = -1e30f, sp = 0.f;

  for (int c = 0; c < 24; ++c) {
    const int m0 = c * 32;
    const short* kc = Kp + (size_t)m0 * DPAD;
    const bf16x8 ka0 = *(const bf16x8*)kc;
    const bf16x8 ka1 = *(const bf16x8*)(kc + 32);
    const bf16x8 kb0 = *(const bf16x8*)(kc + 16 * DPAD);
    const bf16x8 kb1 = *(const bf16x8*)(kc + 16 * DPAD + 32);
    f32x4 d0 = (f32x4){0.f, 0.f, 0.f, 0.f};
    d0 = __builtin_amdgcn_mfma_f32_16x16x32_bf16(ka0, qf0, d0, 0, 0, 0);
    d0 = __builtin_amdgcn_mfma_f32_16x16x32_bf16(ka1, qf1, d0, 0, 0, 0);
    f32x4 d1 = (f32x4){0.f, 0.f, 0.f, 0.f};
    d1 = __builtin_amdgcn_mfma_f32_16x16x32_bf16(kb0, qf0, d1, 0, 0, 0);
    d1 = __builtin_amdgcn_mfma_f32_16x16x32_bf16(kb1, qf1, d1, 0, 0, 0);

    const uint2 bw0 = *(const uint2*)(Bp + m0);
    const uint2 bw1 = *(const uint2*)(Bp + m0 + 16);
    float s[8];
    s[0] = fmaf(d0[0], SC2, blo(bw0.x)); s[1] = fmaf(d0[1], SC2, bhi(bw0.x));
    s[2] = fmaf(d0[2], SC2, blo(bw0.y)); s[3] = fmaf(d0[3], SC2, bhi(bw0.y));
    s[4] = fmaf(d1[0], SC2, blo(bw1.x)); s[5] = fmaf(d1[1], SC2, bhi(bw1.x));
    s[6] = fmaf(d1[2], SC2, blo(bw1.y)); s[7] = fmaf(d1[3], SC2, bhi(bw1.y));

    float mx = s[0];
#pragma unroll
    for (int j = 1; j < 8; ++j) mx = fmaxf(mx, s[j]);
    mx = fmaxf(mx, __shfl_xor(mx, 16));
    mx = fmaxf(mx, __shfl_xor(mx, 32));
    const float mn = fmaxf(m, mx);
    const float al = exp2f(m - mn);
    m = mn;
    float p[8], ss = 0.f;
#pragma unroll
    for (int j = 0; j < 8; ++j) { p[j] = exp2f(s[j] - mn); ss += p[j]; }
    sp = fmaf(sp, al, ss);
#pragma unroll
    for (int i = 0; i < 3; ++i) {
      O[i][0] *= al; O[i][1] *= al; O[i][2] *= al; O[i][3] *= al;
    }
    uint2 w0; w0.x = pk_hu(p[0], p[1]); w0.y = pk_hu(p[2], p[3]);
    uint2 w1; w1.x = pk_hu(p[4], p[5]); w1.y = pk_hu(p[6], p[7]);
    *(uint2*)&sP[w][c & 1][rr][qq * 4] = w0;
    *(uint2*)&sP[w][c & 1][rr][16 + qq * 4] = w1;
    const bf16x8 pf = *(const bf16x8*)&sP[w][c & 1][rr][qq * 8];
#pragma unroll
    for (int dt = 0; dt < 3; ++dt) {
      const bf16x8 vf = *(const bf16x8*)(Vp + (size_t)(dt * 16 + rr) * VSTR + m0);
      O[dt] = __builtin_amdgcn_mfma_f32_16x16x32_bf16(vf, pf, O[dt], 0, 0, 0);
    }
  }

  { // ---- epilogue chunk: m in [768,784), cols [784,800) forced to P=0 ----
    const int m0 = 768;
    const short* kc = Kp + (size_t)m0 * DPAD;
    const bf16x8 ka0 = *(const bf16x8*)kc;
    const bf16x8 ka1 = *(const bf16x8*)(kc + 32);
    f32x4 d0 = (f32x4){0.f, 0.f, 0.f, 0.f};
    d0 = __builtin_amdgcn_mfma_f32_16x16x32_bf16(ka0, qf0, d0, 0, 0, 0);
    d0 = __builtin_amdgcn_mfma_f32_16x16x32_bf16(ka1, qf1, d0, 0, 0, 0);
    const uint2 bw0 = *(const uint2*)(Bp + m0);
    float s[4];
    s[0] = fmaf(d0[0], SC2, blo(bw0.x)); s[1] = fmaf(d0[1], SC2, bhi(bw0.x));
    s[2] = fmaf(d0[2], SC2, blo(bw0.y)); s[3] = fmaf(d0[3], SC2, bhi(bw0.y));
    float mx = fmaxf(fmaxf(s[0], s[1]), fmaxf(s[2], s[3]));
    mx = fmaxf(mx, __shfl_xor(mx, 16));
    mx = fmaxf(mx, __shfl_xor(mx, 32));
    const float mn = fmaxf(m, mx);
    const float al = exp2f(m - mn);
    m = mn;
    float p[4], ss = 0.f;
#pragma unroll
    for (int j = 0; j < 4; ++j) { p[j] = exp2f(s[j] - mn); ss += p[j]; }
    sp = fmaf(sp, al, ss);
#pragma unroll
    for (int i = 0; i < 3; ++i) {
      O[i][0] *= al; O[i][1] *= al; O[i][2] *= al; O[i][3] *= al;
    }
    uint2 w0; w0.x = pk_hu(p[0], p[1]); w0.y = pk_hu(p[2], p[3]);
    *(uint2*)&sP[w][0][rr][qq * 4] = w0;
    *(uint2*)&sP[w][0][rr][16 + qq * 4] = make_uint2(0, 0);
    const bf16x8 pf = *(const bf16x8*)&sP[w][0][rr][qq * 8];
#pragma unroll
    for (int dt = 0; dt < 3; ++dt) {
      const bf16x8 vf = *(const bf16x8*)(Vp + (size_t)(dt * 16 + rr) * VSTR + m0);
      O[dt] = __builtin_amdgcn_mfma_f32_16x16x32_bf16(vf, pf, O[dt], 0, 0, 0);
    }
  }

  // ---- normalize + write AO (b, pix, 384) bf16 ----
  sp += __shfl_xor(sp, 16);
  sp += __shfl_xor(sp, 32);
  const float inv = 1.f / sp;
  short* ao = AO + ((size_t)b * NPIX + q0 + rr) * DIMC + h * HDIM + qq * 4;
#pragma unroll
  for (int dt = 0; dt < 3; ++dt) {
    uint2 pk;
    pk.x = pk_rne(O[dt][0] * inv, O[dt][1] * inv);
    pk.y = pk_rne(O[dt][2] * inv, O[dt][3] * inv);
    *(uint2*)(ao + dt * 16) = pk;
  }
}

// ================= proj GEMM: out(b,c,pix) fp32 = Wp @ AO^T ==========
__global__ __launch_bounds__(256) void proj_gemm(
    const short* __restrict__ Wfp, const float* __restrict__ pb,
    const short* __restrict__ AO, float* __restrict__ out)
{
  const int t = threadIdx.x;
  const int w = t >> 6, lane = t & 63;
  const int rr = lane & 15, qq = lane >> 4;
  const int b = blockIdx.y;
  const int pix = blockIdx.x * 16 + rr;

  const short* Xp = AO + ((size_t)b * NPIX + pix) * DIMC + qq * 8;
  const short* wfp = Wfp + ((size_t)lane * 24 + w) * 8;

  f32x4 acc[6];
#pragma unroll
  for (int i = 0; i < 6; ++i) acc[i] = (f32x4){0.f, 0.f, 0.f, 0.f};

  for (int ks = 0; ks < 12; ++ks) {
    const bf16x8 xf = *(const bf16x8*)(Xp + ks * 32);
#pragma unroll
    for (int i = 0; i < 6; ++i) {
      const bf16x8 af = *(const bf16x8*)(wfp + i * 32);
      acc[i] = __builtin_amdgcn_mfma_f32_16x16x32_bf16(af, xf, acc[i], 0, 0, 0);
    }
    wfp += (size_t)64 * 24 * 8;
  }

#pragma unroll
  for (int i = 0; i < 6; ++i) {
    const int ch0 = (w + 4 * i) * 16 + qq * 4;
    const float4 bv = *(const float4*)(pb + ch0);
    float* o = out + ((size_t)b * DIMC + ch0) * NPIX + pix;
    o[0] = acc[i][0] + bv.x;
    o[NPIX] = acc[i][1] + bv.y;
    o[2 * NPIX] = acc[i][2] + bv.z;
    o[3 * NPIX] = acc[i][3] + bv.w;
  }
}

extern "C" void kernel_launch(void* const* d_in, const int* in_sizes, int n_in,
                              void* d_out, int out_size, void* d_ws, size_t ws_size,
                              hipStream_t stream)
{
  const float* ll     = (const float*)d_in[0];
  const float* ha     = (const float*)d_in[1];
  const float* q_w    = (const float*)d_in[2];
  const float* q_b    = (const float*)d_in[3];
  const float* kv_w   = (const float*)d_in[4];
  const float* kv_b   = (const float*)d_in[5];
  const float* proj_w = (const float*)d_in[6];
  const float* proj_b = (const float*)d_in[7];
  const float* biases = (const float*)d_in[8];
  // d_in[9] (bias_idxs) unused: index == |i1-i2|*28+|j1-j2| (validated R1/R2)
  float* out = (float*)d_out;

  short* Qb   = (short*)d_ws;                               // (b,h,784,64)
  short* Kb   = Qb   + (size_t)NB * NHEAD * NPIX * DPAD;    // (b,h,784,64)
  short* Vb   = Kb   + (size_t)NB * NHEAD * NPIX * DPAD;    // (b,h,48,800)
  short* Xll  = Vb   + (size_t)NB * NHEAD * HDIM * VSTR;    // (b,784,384)
  short* Xha  = Xll  + (size_t)NB * NPIX * DIMC;
  short* AO   = Xha  + (size_t)NB * NPIX * DIMC;            // (b,784,384)
  short* Bt   = AO   + (size_t)NB * NPIX * DIMC;            // (8,784,784)
  short* Wfq  = Bt   + (size_t)NHEAD * NPIX * NPIX;
  short* Wfkv = Wfq  + (size_t)12 * 64 * 24 * 8;
  short* Wfp  = Wfkv + (size_t)12 * 64 * 48 * 8;

  prep_kernel<<<dim3(3960), 256, 0, stream>>>(ll, ha, q_w, kv_w, proj_w, biases,
                                              Xll, Xha, Wfq, Wfkv, Wfp, Bt, Qb, Kb);
  qkv_gemm<<<dim3(49, NB, 3), 256, 0, stream>>>(Wfq, Wfkv, q_b, kv_b, Xll, Xha, Qb, Kb, Vb);
  attn_kernel<<<dim3(13, NHEAD, NB), 256, 0, stream>>>(Qb, Kb, Vb, Bt, AO);
  proj_gemm<<<dim3(49, NB), 256, 0, stream>>>(Wfp, proj_b, AO, out);
}

// Round 4
// 365.176 us; speedup vs baseline: 1.0056x; 1.0056x over previous
//
#include <hip/hip_runtime.h>

#define RES    28
#define DIMC   384
#define NHEAD  8
#define HDIM   48
#define DPAD   64
#define NPIX   784
#define NB     16
#define VSTR   800
#define SC2    0.20823294f    // 48^-0.5 * log2(e)
#define LOG2E  1.44269504f

typedef short bf16x8 __attribute__((ext_vector_type(8)));
typedef float f32x4  __attribute__((ext_vector_type(4)));

__device__ __forceinline__ short f2bf(float x) {
  union { float f; unsigned u; } v; v.f = x;
  return (short)((v.u + 0x7FFFu + ((v.u >> 16) & 1u)) >> 16);   // RNE
}
__device__ __forceinline__ unsigned pk_rne(float a, float b) {
  union { float f; unsigned u; } x, y; x.f = a; y.f = b;
  return __builtin_amdgcn_perm(y.u + 0x7FFFu + ((y.u >> 16) & 1u),
                               x.u + 0x7FFFu + ((x.u >> 16) & 1u), 0x07060302u);
}
__device__ __forceinline__ unsigned pk_hu(float a, float b) {   // round-half-up, 3 ops
  union { float f; unsigned u; } x, y; x.f = a; y.f = b;
  return __builtin_amdgcn_perm(y.u + 0x8000u, x.u + 0x8000u, 0x07060302u);
}
__device__ __forceinline__ float blo(unsigned u) { union { unsigned u; float f; } v; v.u = u << 16; return v.f; }
__device__ __forceinline__ float bhi(unsigned u) { union { unsigned u; float f; } v; v.u = u & 0xFFFF0000u; return v.f; }

// ================= prep: transpose+cvt X, pack W frags, bias matrix, Q/K pad zero ==========
// blocks [0,2496): transpose  [2496,2784): pack  [2784,3176): bias  [3176,3960): pads
__global__ __launch_bounds__(256) void prep_kernel(
    const float* __restrict__ ll, const float* __restrict__ ha,
    const float* __restrict__ qw, const float* __restrict__ kvw, const float* __restrict__ pw,
    const float* __restrict__ biases,
    short* __restrict__ Xll, short* __restrict__ Xha,
    short* __restrict__ Wfq, short* __restrict__ Wfkv, short* __restrict__ Wfp,
    short* __restrict__ Bt, short* __restrict__ Qb, short* __restrict__ Kb)
{
  __shared__ __align__(16) short sT[64][72];
  __shared__ float sB[NPIX];
  const int bid = blockIdx.x, t = threadIdx.x;

  if (bid < 2496) {               // ---- transpose (b,c,pix) f32 -> (b,pix,c) bf16 ----
    const int px = bid % 13, cb = (bid / 13) % 6, zz = bid / 78;
    const int which = zz >> 4, b = zz & 15;
    const float* X = (which ? ha : ll) + (size_t)b * DIMC * NPIX;
    short* T = (which ? Xha : Xll) + (size_t)b * NPIX * DIMC;
    const int c0 = cb * 64, p0 = px * 64;
    const int rrr = t >> 4, pc = (t & 15) * 4;
#pragma unroll
    for (int i = 0; i < 4; ++i) {
      const int c = rrr + 16 * i;
      if (p0 + pc < NPIX) {
        float4 v = *(const float4*)(X + (size_t)(c0 + c) * NPIX + p0 + pc);
        sT[pc + 0][c] = f2bf(v.x); sT[pc + 1][c] = f2bf(v.y);
        sT[pc + 2][c] = f2bf(v.z); sT[pc + 3][c] = f2bf(v.w);
      }
    }
    __syncthreads();
    const int pr = t >> 3, cc = (t & 7) * 8;
#pragma unroll
    for (int i = 0; i < 2; ++i) {
      const int p = pr + 32 * i;
      if (p0 + p < NPIX)
        *(bf16x8*)(T + (size_t)(p0 + p) * DIMC + c0 + cc) = *(const bf16x8*)&sT[p][cc];
    }
  } else if (bid < 2784) {        // ---- pack W -> Wf[ks][lane][mtile][8] ----
    int gid = (bid - 2496) * 256 + t;
    const float* W; short* O; int Mtot;
    if (gid < 18432)      { W = qw;  O = Wfq;  Mtot = 24; }
    else if (gid < 55296) { W = kvw; O = Wfkv; Mtot = 48; gid -= 18432; }
    else                  { W = pw;  O = Wfp;  Mtot = 24; gid -= 55296; }
    const int mtile = gid % Mtot;
    const int lk = gid / Mtot;
    const int lane = lk & 63, ks = lk >> 6;
    const int row = mtile * 16 + (lane & 15);
    const int k = ks * 32 + (lane >> 4) * 8;
    const float* src = W + (size_t)row * DIMC + k;
    const float4 a = *(const float4*)src;
    const float4 b = *(const float4*)(src + 4);
    bf16x8 o;
    o[0] = f2bf(a.x); o[1] = f2bf(a.y); o[2] = f2bf(a.z); o[3] = f2bf(a.w);
    o[4] = f2bf(b.x); o[5] = f2bf(b.y); o[6] = f2bf(b.z); o[7] = f2bf(b.w);
    *(bf16x8*)(O + (size_t)gid * 8) = o;
  } else if (bid < 3176) {        // ---- bias matrix Bt[h][n][m] = bias*log2e, bf16 ----
    const int bb = bid - 2784;
    const int h = bb / 49, mt = bb % 49;
    for (int i = t; i < NPIX; i += 256) sB[i] = biases[h * NPIX + i] * LOG2E;
    __syncthreads();
    const int mrow = mt * 16 + (t >> 4);
    const int i2 = mrow / RES, j2 = mrow - i2 * RES;
    short* orow = Bt + ((size_t)h * NPIX + mrow) * NPIX;
    for (int n0 = (t & 15) * 4; n0 < NPIX; n0 += 64) {
      float v[4];
#pragma unroll
      for (int u = 0; u < 4; ++u) {
        const int n = n0 + u;
        const int i1 = n / RES, j1 = n - i1 * RES;
        int di = i1 - i2; di = di < 0 ? -di : di;
        int dj = j1 - j2; dj = dj < 0 ? -dj : dj;
        v[u] = sB[di * RES + dj];
      }
      uint2 pk; pk.x = pk_rne(v[0], v[1]); pk.y = pk_rne(v[2], v[3]);
      *(uint2*)(orow + n0) = pk;
    }
  } else {                        // ---- zero Q/K pad cols d in [48,64) ----
    const int pp = bid - 3176;
    short* buf = (pp >= 392) ? Kb : Qb;
    const size_t r = (size_t)(pp % 392) * 256 + t;
    short* p = buf + r * DPAD + HDIM;
    *(int4*)p = make_int4(0, 0, 0, 0);
    *(int4*)(p + 8) = make_int4(0, 0, 0, 0);
  }
}

// ================= Q GEMM: 24 mtiles, from Xll ==========
__global__ __launch_bounds__(256) void gemm_q(
    const short* __restrict__ Wf, const float* __restrict__ bias,
    const short* __restrict__ Xt, short* __restrict__ Qb)
{
  const int t = threadIdx.x;
  const int w = t >> 6, lane = t & 63;
  const int rr = lane & 15, qq = lane >> 4;
  const int b = blockIdx.y;
  const int pix = blockIdx.x * 16 + rr;

  const short* Xp = Xt + ((size_t)b * NPIX + pix) * DIMC + qq * 8;
  const short* wfp = Wf + ((size_t)lane * 24 + w) * 8;

  f32x4 acc[6];
#pragma unroll
  for (int i = 0; i < 6; ++i) acc[i] = (f32x4){0.f, 0.f, 0.f, 0.f};

  for (int ks = 0; ks < 12; ++ks) {
    const bf16x8 xf = *(const bf16x8*)(Xp + ks * 32);
#pragma unroll
    for (int i = 0; i < 6; ++i) {
      const bf16x8 af = *(const bf16x8*)(wfp + i * 32);
      acc[i] = __builtin_amdgcn_mfma_f32_16x16x32_bf16(af, xf, acc[i], 0, 0, 0);
    }
    wfp += (size_t)64 * 24 * 8;
  }
#pragma unroll
  for (int i = 0; i < 6; ++i) {
    const int chl = (w + 4 * i) * 16 + qq * 4;
    const float4 bv = *(const float4*)(bias + chl);
    const int hh = chl / HDIM, d0 = chl % HDIM;
    uint2 pk;
    pk.x = pk_rne(acc[i][0] + bv.x, acc[i][1] + bv.y);
    pk.y = pk_rne(acc[i][2] + bv.z, acc[i][3] + bv.w);
    *(uint2*)(Qb + (((size_t)b * NHEAD + hh) * NPIX + pix) * DPAD + d0) = pk;
  }
}

// ================= KV GEMM: 48 mtiles in one block (single Xha read) ==========
__global__ __launch_bounds__(256) void gemm_kv(
    const short* __restrict__ Wf, const float* __restrict__ bias,
    const short* __restrict__ Xt, short* __restrict__ Kb, short* __restrict__ Vb)
{
  const int t = threadIdx.x;
  const int w = t >> 6, lane = t & 63;
  const int rr = lane & 15, qq = lane >> 4;
  const int b = blockIdx.y;
  const int pix = blockIdx.x * 16 + rr;

  const short* Xp = Xt + ((size_t)b * NPIX + pix) * DIMC + qq * 8;
  const short* wfp = Wf + ((size_t)lane * 48 + w) * 8;

  f32x4 acc[12];
#pragma unroll
  for (int i = 0; i < 12; ++i) acc[i] = (f32x4){0.f, 0.f, 0.f, 0.f};

  for (int ks = 0; ks < 12; ++ks) {
    const bf16x8 xf = *(const bf16x8*)(Xp + ks * 32);
#pragma unroll
    for (int i = 0; i < 12; ++i) {
      const bf16x8 af = *(const bf16x8*)(wfp + i * 32);
      acc[i] = __builtin_amdgcn_mfma_f32_16x16x32_bf16(af, xf, acc[i], 0, 0, 0);
    }
    wfp += (size_t)64 * 48 * 8;
  }
#pragma unroll
  for (int i = 0; i < 12; ++i) {
    const int chl = (w + 4 * i) * 16 + qq * 4;
    const float4 bv = *(const float4*)(bias + chl);
    const float v0 = acc[i][0] + bv.x, v1 = acc[i][1] + bv.y;
    const float v2 = acc[i][2] + bv.z, v3 = acc[i][3] + bv.w;
    if (chl < DIMC) {                                  // K: (b,h,pix,DPAD)
      const int hh = chl / HDIM, d0 = chl % HDIM;
      uint2 pk; pk.x = pk_rne(v0, v1); pk.y = pk_rne(v2, v3);
      *(uint2*)(Kb + (((size_t)b * NHEAD + hh) * NPIX + pix) * DPAD + d0) = pk;
    } else {                                           // V: (b,h,d,VSTR)
      const int ch2 = chl - DIMC;
      const int hh = ch2 / HDIM, d0 = ch2 % HDIM;
      short* o = Vb + (((size_t)b * NHEAD + hh) * HDIM + d0) * VSTR + pix;
      o[0] = f2bf(v0); o[VSTR] = f2bf(v1); o[2 * VSTR] = f2bf(v2); o[3 * VSTR] = f2bf(v3);
    }
  }
}

// ================= attention: one WAVE = 32 q-rows (2 tiles, 2 indep softmax chains) ====
// XCD pinning: h = blockIdx.x & 7 -> all blocks touching Bt[h] live on one XCD (L2-resident).
struct Chain { float m, sp; f32x4 O0, O1, O2; };

__device__ __forceinline__ void chain_init(Chain& c) {
  c.m = -1e30f; c.sp = 0.f;
  c.O0 = (f32x4){0.f,0.f,0.f,0.f}; c.O1 = c.O0; c.O2 = c.O0;
}

// full 32-col chunk step for one chain: bias+softmax+rescale+pack P into sPt[16][40]
__device__ __forceinline__ void chain_step(
    Chain& c, const f32x4 d0, const f32x4 d1, const uint2 bw0, const uint2 bw1,
    short* sPt, const int rr, const int qq)
{
  float s[8];
  s[0] = fmaf(d0[0], SC2, blo(bw0.x)); s[1] = fmaf(d0[1], SC2, bhi(bw0.x));
  s[2] = fmaf(d0[2], SC2, blo(bw0.y)); s[3] = fmaf(d0[3], SC2, bhi(bw0.y));
  s[4] = fmaf(d1[0], SC2, blo(bw1.x)); s[5] = fmaf(d1[1], SC2, bhi(bw1.x));
  s[6] = fmaf(d1[2], SC2, blo(bw1.y)); s[7] = fmaf(d1[3], SC2, bhi(bw1.y));
  float mx = s[0];
#pragma unroll
  for (int j = 1; j < 8; ++j) mx = fmaxf(mx, s[j]);
  mx = fmaxf(mx, __shfl_xor(mx, 16));
  mx = fmaxf(mx, __shfl_xor(mx, 32));
  const float mn = fmaxf(c.m, mx);
  const float al = exp2f(c.m - mn);
  c.m = mn;
  float p[8], ss = 0.f;
#pragma unroll
  for (int j = 0; j < 8; ++j) { p[j] = exp2f(s[j] - mn); ss += p[j]; }
  c.sp = fmaf(c.sp, al, ss);
  c.O0 *= al; c.O1 *= al; c.O2 *= al;
  uint2 w0; w0.x = pk_hu(p[0], p[1]); w0.y = pk_hu(p[2], p[3]);
  uint2 w1; w1.x = pk_hu(p[4], p[5]); w1.y = pk_hu(p[6], p[7]);
  *(uint2*)(sPt + rr * 40 + qq * 4) = w0;
  *(uint2*)(sPt + rr * 40 + 16 + qq * 4) = w1;
}

// tail chunk (16 cols): d1 half zeroed
__device__ __forceinline__ void chain_tail(
    Chain& c, const f32x4 d0, const uint2 bw0,
    short* sPt, const int rr, const int qq)
{
  float s[4];
  s[0] = fmaf(d0[0], SC2, blo(bw0.x)); s[1] = fmaf(d0[1], SC2, bhi(bw0.x));
  s[2] = fmaf(d0[2], SC2, blo(bw0.y)); s[3] = fmaf(d0[3], SC2, bhi(bw0.y));
  float mx = fmaxf(fmaxf(s[0], s[1]), fmaxf(s[2], s[3]));
  mx = fmaxf(mx, __shfl_xor(mx, 16));
  mx = fmaxf(mx, __shfl_xor(mx, 32));
  const float mn = fmaxf(c.m, mx);
  const float al = exp2f(c.m - mn);
  c.m = mn;
  float p[4], ss = 0.f;
#pragma unroll
  for (int j = 0; j < 4; ++j) { p[j] = exp2f(s[j] - mn); ss += p[j]; }
  c.sp = fmaf(c.sp, al, ss);
  c.O0 *= al; c.O1 *= al; c.O2 *= al;
  uint2 w0; w0.x = pk_hu(p[0], p[1]); w0.y = pk_hu(p[2], p[3]);
  *(uint2*)(sPt + rr * 40 + qq * 4) = w0;
  *(uint2*)(sPt + rr * 40 + 16 + qq * 4) = make_uint2(0, 0);
}

__global__ __launch_bounds__(256) void attn_kernel(
    const short* __restrict__ Q, const short* __restrict__ K,
    const short* __restrict__ V, const short* __restrict__ Bt,
    short* __restrict__ AO)
{
  __shared__ __align__(16) short sP[4][2][16 * 40];
  const int t = threadIdx.x;
  const int w = t >> 6, lane = t & 63;
  const int rr = lane & 15, qq = lane >> 4;
  const int x = blockIdx.x;            // 896 = 7*16*8
  const int h = x & 7;                 // XCD = x % 8 -> one head per XCD
  const int i = x >> 3;                // 0..111
  const int pb = i % 7, b = i / 7;     // 7 consecutive same-XCD blocks share (b,h)
  const int p = pb * 4 + w;            // q-tile pair 0..27
  if (p >= 25) return;
  const int qA = p * 32;
  const bool hasB = (qA + 16 < NPIX);
  const int qBr = hasB ? qA + 16 : qA;
  const int bh = b * NHEAD + h;

  const short* QpA = Q + ((size_t)bh * NPIX + qA + rr) * DPAD + qq * 8;
  const short* QpB = Q + ((size_t)bh * NPIX + qBr + rr) * DPAD + qq * 8;
  const bf16x8 qfA0 = *(const bf16x8*)QpA;
  const bf16x8 qfA1 = *(const bf16x8*)(QpA + 32);
  const bf16x8 qfB0 = *(const bf16x8*)QpB;
  const bf16x8 qfB1 = *(const bf16x8*)(QpB + 32);

  const short* Kp = K + ((size_t)bh * NPIX + rr) * DPAD + qq * 8;
  const short* Vp = V + (size_t)bh * HDIM * VSTR + qq * 8;
  const short* BpA = Bt + ((size_t)h * NPIX + qA + rr) * NPIX + qq * 4;
  const short* BpB = Bt + ((size_t)h * NPIX + qBr + rr) * NPIX + qq * 4;
  short* sPA = &sP[w][0][0];
  short* sPB = &sP[w][1][0];

  Chain cA, cB;
  chain_init(cA); chain_init(cB);

  for (int c = 0; c < 24; ++c) {
    const int m0 = c * 32;
    const short* kc = Kp + (size_t)m0 * DPAD;
    const bf16x8 ka0 = *(const bf16x8*)kc;
    const bf16x8 ka1 = *(const bf16x8*)(kc + 32);
    const bf16x8 kb0 = *(const bf16x8*)(kc + 16 * DPAD);
    const bf16x8 kb1 = *(const bf16x8*)(kc + 16 * DPAD + 32);

    f32x4 dA0 = (f32x4){0.f,0.f,0.f,0.f}, dA1 = dA0, dB0 = dA0, dB1 = dA0;
    dA0 = __builtin_amdgcn_mfma_f32_16x16x32_bf16(ka0, qfA0, dA0, 0, 0, 0);
    dA0 = __builtin_amdgcn_mfma_f32_16x16x32_bf16(ka1, qfA1, dA0, 0, 0, 0);
    dB0 = __builtin_amdgcn_mfma_f32_16x16x32_bf16(ka0, qfB0, dB0, 0, 0, 0);
    dB0 = __builtin_amdgcn_mfma_f32_16x16x32_bf16(ka1, qfB1, dB0, 0, 0, 0);
    dA1 = __builtin_amdgcn_mfma_f32_16x16x32_bf16(kb0, qfA0, dA1, 0, 0, 0);
    dA1 = __builtin_amdgcn_mfma_f32_16x16x32_bf16(kb1, qfA1, dA1, 0, 0, 0);
    dB1 = __builtin_amdgcn_mfma_f32_16x16x32_bf16(kb0, qfB0, dB1, 0, 0, 0);
    dB1 = __builtin_amdgcn_mfma_f32_16x16x32_bf16(kb1, qfB1, dB1, 0, 0, 0);

    const uint2 bwA0 = *(const uint2*)(BpA + m0);
    const uint2 bwA1 = *(const uint2*)(BpA + m0 + 16);
    const uint2 bwB0 = *(const uint2*)(BpB + m0);
    const uint2 bwB1 = *(const uint2*)(BpB + m0 + 16);

    chain_step(cA, dA0, dA1, bwA0, bwA1, sPA, rr, qq);
    chain_step(cB, dB0, dB1, bwB0, bwB1, sPB, rr, qq);

    const bf16x8 vf0 = *(const bf16x8*)(Vp + (size_t)rr * VSTR + m0);
    const bf16x8 vf1 = *(const bf16x8*)(Vp + (size_t)(16 + rr) * VSTR + m0);
    const bf16x8 vf2 = *(const bf16x8*)(Vp + (size_t)(32 + rr) * VSTR + m0);
    const bf16x8 pfA = *(const bf16x8*)(sPA + rr * 40 + qq * 8);
    const bf16x8 pfB = *(const bf16x8*)(sPB + rr * 40 + qq * 8);
    cA.O0 = __builtin_amdgcn_mfma_f32_16x16x32_bf16(vf0, pfA, cA.O0, 0, 0, 0);
    cA.O1 = __builtin_amdgcn_mfma_f32_16x16x32_bf16(vf1, pfA, cA.O1, 0, 0, 0);
    cA.O2 = __builtin_amdgcn_mfma_f32_16x16x32_bf16(vf2, pfA, cA.O2, 0, 0, 0);
    cB.O0 = __builtin_amdgcn_mfma_f32_16x16x32_bf16(vf0, pfB, cB.O0, 0, 0, 0);
    cB.O1 = __builtin_amdgcn_mfma_f32_16x16x32_bf16(vf1, pfB, cB.O1, 0, 0, 0);
    cB.O2 = __builtin_amdgcn_mfma_f32_16x16x32_bf16(vf2, pfB, cB.O2, 0, 0, 0);
  }

  { // ---- tail chunk: m in [768,784) ----
    const int m0 = 768;
    const short* kc = Kp + (size_t)m0 * DPAD;
    const bf16x8 ka0 = *(const bf16x8*)kc;
    const bf16x8 ka1 = *(const bf16x8*)(kc + 32);
    f32x4 dA0 = (f32x4){0.f,0.f,0.f,0.f}, dB0 = dA0;
    dA0 = __builtin_amdgcn_mfma_f32_16x16x32_bf16(ka0, qfA0, dA0, 0, 0, 0);
    dA0 = __builtin_amdgcn_mfma_f32_16x16x32_bf16(ka1, qfA1, dA0, 0, 0, 0);
    dB0 = __builtin_amdgcn_mfma_f32_16x16x32_bf16(ka0, qfB0, dB0, 0, 0, 0);
    dB0 = __builtin_amdgcn_mfma_f32_16x16x32_bf16(ka1, qfB1, dB0, 0, 0, 0);
    const uint2 bwA0 = *(const uint2*)(BpA + m0);
    const uint2 bwB0 = *(const uint2*)(BpB + m0);
    chain_tail(cA, dA0, bwA0, sPA, rr, qq);
    chain_tail(cB, dB0, bwB0, sPB, rr, qq);
    const bf16x8 vf0 = *(const bf16x8*)(Vp + (size_t)rr * VSTR + m0);
    const bf16x8 vf1 = *(const bf16x8*)(Vp + (size_t)(16 + rr) * VSTR + m0);
    const bf16x8 vf2 = *(const bf16x8*)(Vp + (size_t)(32 + rr) * VSTR + m0);
    const bf16x8 pfA = *(const bf16x8*)(sPA + rr * 40 + qq * 8);
    const bf16x8 pfB = *(const bf16x8*)(sPB + rr * 40 + qq * 8);
    cA.O0 = __builtin_amdgcn_mfma_f32_16x16x32_bf16(vf0, pfA, cA.O0, 0, 0, 0);
    cA.O1 = __builtin_amdgcn_mfma_f32_16x16x32_bf16(vf1, pfA, cA.O1, 0, 0, 0);
    cA.O2 = __builtin_amdgcn_mfma_f32_16x16x32_bf16(vf2, pfA, cA.O2, 0, 0, 0);
    cB.O0 = __builtin_amdgcn_mfma_f32_16x16x32_bf16(vf0, pfB, cB.O0, 0, 0, 0);
    cB.O1 = __builtin_amdgcn_mfma_f32_16x16x32_bf16(vf1, pfB, cB.O1, 0, 0, 0);
    cB.O2 = __builtin_amdgcn_mfma_f32_16x16x32_bf16(vf2, pfB, cB.O2, 0, 0, 0);
  }

  // ---- normalize + store AO (b, pix, 384) bf16 ----
  {
    float sA = cA.sp;
    sA += __shfl_xor(sA, 16); sA += __shfl_xor(sA, 32);
    const float invA = 1.f / sA;
    short* ao = AO + ((size_t)b * NPIX + qA + rr) * DIMC + h * HDIM + qq * 4;
    uint2 pk;
    pk.x = pk_rne(cA.O0[0] * invA, cA.O0[1] * invA);
    pk.y = pk_rne(cA.O0[2] * invA, cA.O0[3] * invA);
    *(uint2*)ao = pk;
    pk.x = pk_rne(cA.O1[0] * invA, cA.O1[1] * invA);
    pk.y = pk_rne(cA.O1[2] * invA, cA.O1[3] * invA);
    *(uint2*)(ao + 16) = pk;
    pk.x = pk_rne(cA.O2[0] * invA, cA.O2[1] * invA);
    pk.y = pk_rne(cA.O2[2] * invA, cA.O2[3] * invA);
    *(uint2*)(ao + 32) = pk;
  }
  if (hasB) {
    float sB2 = cB.sp;
    sB2 += __shfl_xor(sB2, 16); sB2 += __shfl_xor(sB2, 32);
    const float invB = 1.f / sB2;
    short* ao = AO + ((size_t)b * NPIX + qA + 16 + rr) * DIMC + h * HDIM + qq * 4;
    uint2 pk;
    pk.x = pk_rne(cB.O0[0] * invB, cB.O0[1] * invB);
    pk.y = pk_rne(cB.O0[2] * invB, cB.O0[3] * invB);
    *(uint2*)ao = pk;
    pk.x = pk_rne(cB.O1[0] * invB, cB.O1[1] * invB);
    pk.y = pk_rne(cB.O1[2] * invB, cB.O1[3] * invB);
    *(uint2*)(ao + 16) = pk;
    pk.x = pk_rne(cB.O2[0] * invB, cB.O2[1] * invB);
    pk.y = pk_rne(cB.O2[2] * invB, cB.O2[3] * invB);
    *(uint2*)(ao + 32) = pk;
  }
}

// ================= proj GEMM: out(b,c,pix) fp32 = Wp @ AO^T ==========
__global__ __launch_bounds__(256) void proj_gemm(
    const short* __restrict__ Wfp, const float* __restrict__ pb,
    const short* __restrict__ AO, float* __restrict__ out)
{
  const int t = threadIdx.x;
  const int w = t >> 6, lane = t & 63;
  const int rr = lane & 15, qq = lane >> 4;
  const int b = blockIdx.y;
  const int pix = blockIdx.x * 16 + rr;

  const short* Xp = AO + ((size_t)b * NPIX + pix) * DIMC + qq * 8;
  const short* wfp = Wfp + ((size_t)lane * 24 + w) * 8;

  f32x4 acc[6];
#pragma unroll
  for (int i = 0; i < 6; ++i) acc[i] = (f32x4){0.f, 0.f, 0.f, 0.f};

  for (int ks = 0; ks < 12; ++ks) {
    const bf16x8 xf = *(const bf16x8*)(Xp + ks * 32);
#pragma unroll
    for (int i = 0; i < 6; ++i) {
      const bf16x8 af = *(const bf16x8*)(wfp + i * 32);
      acc[i] = __builtin_amdgcn_mfma_f32_16x16x32_bf16(af, xf, acc[i], 0, 0, 0);
    }
    wfp += (size_t)64 * 24 * 8;
  }
#pragma unroll
  for (int i = 0; i < 6; ++i) {
    const int ch0 = (w + 4 * i) * 16 + qq * 4;
    const float4 bv = *(const float4*)(pb + ch0);
    float* o = out + ((size_t)b * DIMC + ch0) * NPIX + pix;
    o[0] = acc[i][0] + bv.x;
    o[NPIX] = acc[i][1] + bv.y;
    o[2 * NPIX] = acc[i][2] + bv.z;
    o[3 * NPIX] = acc[i][3] + bv.w;
  }
}

extern "C" void kernel_launch(void* const* d_in, const int* in_sizes, int n_in,
                              void* d_out, int out_size, void* d_ws, size_t ws_size,
                              hipStream_t stream)
{
  const float* ll     = (const float*)d_in[0];
  const float* ha     = (const float*)d_in[1];
  const float* q_w    = (const float*)d_in[2];
  const float* q_b    = (const float*)d_in[3];
  const float* kv_w   = (const float*)d_in[4];
  const float* kv_b   = (const float*)d_in[5];
  const float* proj_w = (const float*)d_in[6];
  const float* proj_b = (const float*)d_in[7];
  const float* biases = (const float*)d_in[8];
  // d_in[9] (bias_idxs) unused: index == |i1-i2|*28+|j1-j2| (validated R1/R2)
  float* out = (float*)d_out;

  short* Qb   = (short*)d_ws;                               // (b,h,784,64)
  short* Kb   = Qb   + (size_t)NB * NHEAD * NPIX * DPAD;    // (b,h,784,64)
  short* Vb   = Kb   + (size_t)NB * NHEAD * NPIX * DPAD;    // (b,h,48,800)
  short* Xll  = Vb   + (size_t)NB * NHEAD * HDIM * VSTR;    // (b,784,384)
  short* Xha  = Xll  + (size_t)NB * NPIX * DIMC;
  short* AO   = Xha  + (size_t)NB * NPIX * DIMC;            // (b,784,384)
  short* Bt   = AO   + (size_t)NB * NPIX * DIMC;            // (8,784,784)
  short* Wfq  = Bt   + (size_t)NHEAD * NPIX * NPIX;
  short* Wfkv = Wfq  + (size_t)12 * 64 * 24 * 8;
  short* Wfp  = Wfkv + (size_t)12 * 64 * 48 * 8;

  prep_kernel<<<dim3(3960), 256, 0, stream>>>(ll, ha, q_w, kv_w, proj_w, biases,
                                              Xll, Xha, Wfq, Wfkv, Wfp, Bt, Qb, Kb);
  gemm_q<<<dim3(49, NB), 256, 0, stream>>>(Wfq, q_b, Xll, Qb);
  gemm_kv<<<dim3(49, NB), 256, 0, stream>>>(Wfkv, kv_b, Xha, Kb, Vb);
  attn_kernel<<<dim3(896), 256, 0, stream>>>(Qb, Kb, Vb, Bt, AO);
  proj_gemm<<<dim3(49, NB), 256, 0, stream>>>(Wfp, proj_b, AO, out);
}

// Round 5
// 316.272 us; speedup vs baseline: 1.1611x; 1.1546x over previous
//
#include <hip/hip_runtime.h>

#define RES    28
#define DIMC   384
#define NHEAD  8
#define HDIM   48
#define DPAD   64
#define NPIX   784
#define NB     16
#define VSTR   800
#define SC2    0.20823294f    // 48^-0.5 * log2(e)
#define LOG2E  1.44269504f

typedef short bf16x8 __attribute__((ext_vector_type(8)));
typedef float f32x4  __attribute__((ext_vector_type(4)));

__device__ __forceinline__ short f2bf(float x) {
  union { float f; unsigned u; } v; v.f = x;
  return (short)((v.u + 0x7FFFu + ((v.u >> 16) & 1u)) >> 16);   // RNE
}
__device__ __forceinline__ unsigned pk_rne(float a, float b) {
  union { float f; unsigned u; } x, y; x.f = a; y.f = b;
  return __builtin_amdgcn_perm(y.u + 0x7FFFu + ((y.u >> 16) & 1u),
                               x.u + 0x7FFFu + ((x.u >> 16) & 1u), 0x07060302u);
}
__device__ __forceinline__ unsigned pk_hu(float a, float b) {   // round-half-up, 3 ops
  union { float f; unsigned u; } x, y; x.f = a; y.f = b;
  return __builtin_amdgcn_perm(y.u + 0x8000u, x.u + 0x8000u, 0x07060302u);
}
__device__ __forceinline__ float blo(unsigned u) { union { unsigned u; float f; } v; v.u = u << 16; return v.f; }
__device__ __forceinline__ float bhi(unsigned u) { union { unsigned u; float f; } v; v.u = u & 0xFFFF0000u; return v.f; }

// ================= prep: transpose+cvt X, pack W frags, bias matrix, Q/K pad zero ==========
// blocks [0,2496): transpose  [2496,2784): pack  [2784,3176): bias  [3176,3960): pads
// Wf layout: [mtile][ks][lane][8] -> lane stride 16B, fragment loads fully coalesced
// (R3/R4 used [ks][lane][mtile]: lane stride 768B = 64-line gather per load -> 98us gemm_kv)
__global__ __launch_bounds__(256) void prep_kernel(
    const float* __restrict__ ll, const float* __restrict__ ha,
    const float* __restrict__ qw, const float* __restrict__ kvw, const float* __restrict__ pw,
    const float* __restrict__ biases,
    short* __restrict__ Xll, short* __restrict__ Xha,
    short* __restrict__ Wfq, short* __restrict__ Wfkv, short* __restrict__ Wfp,
    short* __restrict__ Bt, short* __restrict__ Qb, short* __restrict__ Kb)
{
  __shared__ __align__(16) short sT[64][72];
  __shared__ float sB[NPIX];
  const int bid = blockIdx.x, t = threadIdx.x;

  if (bid < 2496) {               // ---- transpose (b,c,pix) f32 -> (b,pix,c) bf16 ----
    const int px = bid % 13, cb = (bid / 13) % 6, zz = bid / 78;
    const int which = zz >> 4, b = zz & 15;
    const float* X = (which ? ha : ll) + (size_t)b * DIMC * NPIX;
    short* T = (which ? Xha : Xll) + (size_t)b * NPIX * DIMC;
    const int c0 = cb * 64, p0 = px * 64;
    const int rrr = t >> 4, pc = (t & 15) * 4;
#pragma unroll
    for (int i = 0; i < 4; ++i) {
      const int c = rrr + 16 * i;
      if (p0 + pc < NPIX) {
        float4 v = *(const float4*)(X + (size_t)(c0 + c) * NPIX + p0 + pc);
        sT[pc + 0][c] = f2bf(v.x); sT[pc + 1][c] = f2bf(v.y);
        sT[pc + 2][c] = f2bf(v.z); sT[pc + 3][c] = f2bf(v.w);
      }
    }
    __syncthreads();
    const int pr = t >> 3, cc = (t & 7) * 8;
#pragma unroll
    for (int i = 0; i < 2; ++i) {
      const int p = pr + 32 * i;
      if (p0 + p < NPIX)
        *(bf16x8*)(T + (size_t)(p0 + p) * DIMC + c0 + cc) = *(const bf16x8*)&sT[p][cc];
    }
  } else if (bid < 2784) {        // ---- pack W -> Wf[mtile][ks][lane][8] (coalesced) ----
    int gid = (bid - 2496) * 256 + t;
    const float* W; short* O;
    if (gid < 18432)      { W = qw;  O = Wfq; }
    else if (gid < 55296) { W = kvw; O = Wfkv; gid -= 18432; }
    else                  { W = pw;  O = Wfp;  gid -= 55296; }
    const int lane = gid & 63;
    const int ks = (gid >> 6) % 12;
    const int mtile = gid / (64 * 12);
    const int row = mtile * 16 + (lane & 15);
    const int k = ks * 32 + (lane >> 4) * 8;
    const float* src = W + (size_t)row * DIMC + k;
    const float4 a = *(const float4*)src;
    const float4 b = *(const float4*)(src + 4);
    bf16x8 o;
    o[0] = f2bf(a.x); o[1] = f2bf(a.y); o[2] = f2bf(a.z); o[3] = f2bf(a.w);
    o[4] = f2bf(b.x); o[5] = f2bf(b.y); o[6] = f2bf(b.z); o[7] = f2bf(b.w);
    *(bf16x8*)(O + (size_t)gid * 8) = o;
  } else if (bid < 3176) {        // ---- bias matrix Bt[h][n][m] = bias*log2e, bf16 ----
    const int bb = bid - 2784;
    const int h = bb / 49, mt = bb % 49;
    for (int i = t; i < NPIX; i += 256) sB[i] = biases[h * NPIX + i] * LOG2E;
    __syncthreads();
    const int mrow = mt * 16 + (t >> 4);
    const int i2 = mrow / RES, j2 = mrow - i2 * RES;
    short* orow = Bt + ((size_t)h * NPIX + mrow) * NPIX;
    for (int n0 = (t & 15) * 4; n0 < NPIX; n0 += 64) {
      float v[4];
#pragma unroll
      for (int u = 0; u < 4; ++u) {
        const int n = n0 + u;
        const int i1 = n / RES, j1 = n - i1 * RES;
        int di = i1 - i2; di = di < 0 ? -di : di;
        int dj = j1 - j2; dj = dj < 0 ? -dj : dj;
        v[u] = sB[di * RES + dj];
      }
      uint2 pk; pk.x = pk_rne(v[0], v[1]); pk.y = pk_rne(v[2], v[3]);
      *(uint2*)(orow + n0) = pk;
    }
  } else {                        // ---- zero Q/K pad cols d in [48,64) ----
    const int pp = bid - 3176;
    short* buf = (pp >= 392) ? Kb : Qb;
    const size_t r = (size_t)(pp % 392) * 256 + t;
    short* p = buf + r * DPAD + HDIM;
    *(int4*)p = make_int4(0, 0, 0, 0);
    *(int4*)(p + 8) = make_int4(0, 0, 0, 0);
  }
}

// ================= Q GEMM: 24 mtiles, from Xll ==========
// af(i,ks) at Wf + ((w+4i)*12 + ks)*512 + lane*8  -> per-i 24576, per-ks 512 (shorts)
__global__ __launch_bounds__(256) void gemm_q(
    const short* __restrict__ Wf, const float* __restrict__ bias,
    const short* __restrict__ Xt, short* __restrict__ Qb)
{
  const int t = threadIdx.x;
  const int w = t >> 6, lane = t & 63;
  const int rr = lane & 15, qq = lane >> 4;
  const int b = blockIdx.y;
  const int pix = blockIdx.x * 16 + rr;

  const short* Xp = Xt + ((size_t)b * NPIX + pix) * DIMC + qq * 8;
  const short* wfp = Wf + ((size_t)w * 12 * 64 + lane) * 8;

  f32x4 acc[6];
#pragma unroll
  for (int i = 0; i < 6; ++i) acc[i] = (f32x4){0.f, 0.f, 0.f, 0.f};

  for (int ks = 0; ks < 12; ++ks) {
    const bf16x8 xf = *(const bf16x8*)(Xp + ks * 32);
#pragma unroll
    for (int i = 0; i < 6; ++i) {
      const bf16x8 af = *(const bf16x8*)(wfp + (size_t)i * 24576 + ks * 512);
      acc[i] = __builtin_amdgcn_mfma_f32_16x16x32_bf16(af, xf, acc[i], 0, 0, 0);
    }
  }
#pragma unroll
  for (int i = 0; i < 6; ++i) {
    const int chl = (w + 4 * i) * 16 + qq * 4;
    const float4 bv = *(const float4*)(bias + chl);
    const int hh = chl / HDIM, d0 = chl % HDIM;
    uint2 pk;
    pk.x = pk_rne(acc[i][0] + bv.x, acc[i][1] + bv.y);
    pk.y = pk_rne(acc[i][2] + bv.z, acc[i][3] + bv.w);
    *(uint2*)(Qb + (((size_t)b * NHEAD + hh) * NPIX + pix) * DPAD + d0) = pk;
  }
}

// ================= KV GEMM: 48 mtiles in one block (single Xha read) ==========
__global__ __launch_bounds__(256) void gemm_kv(
    const short* __restrict__ Wf, const float* __restrict__ bias,
    const short* __restrict__ Xt, short* __restrict__ Kb, short* __restrict__ Vb)
{
  const int t = threadIdx.x;
  const int w = t >> 6, lane = t & 63;
  const int rr = lane & 15, qq = lane >> 4;
  const int b = blockIdx.y;
  const int pix = blockIdx.x * 16 + rr;

  const short* Xp = Xt + ((size_t)b * NPIX + pix) * DIMC + qq * 8;
  const short* wfp = Wf + ((size_t)w * 12 * 64 + lane) * 8;

  f32x4 acc[12];
#pragma unroll
  for (int i = 0; i < 12; ++i) acc[i] = (f32x4){0.f, 0.f, 0.f, 0.f};

  for (int ks = 0; ks < 12; ++ks) {
    const bf16x8 xf = *(const bf16x8*)(Xp + ks * 32);
#pragma unroll
    for (int i = 0; i < 12; ++i) {
      const bf16x8 af = *(const bf16x8*)(wfp + (size_t)i * 24576 + ks * 512);
      acc[i] = __builtin_amdgcn_mfma_f32_16x16x32_bf16(af, xf, acc[i], 0, 0, 0);
    }
  }
#pragma unroll
  for (int i = 0; i < 12; ++i) {
    const int chl = (w + 4 * i) * 16 + qq * 4;
    const float4 bv = *(const float4*)(bias + chl);
    const float v0 = acc[i][0] + bv.x, v1 = acc[i][1] + bv.y;
    const float v2 = acc[i][2] + bv.z, v3 = acc[i][3] + bv.w;
    if (chl < DIMC) {                                  // K: (b,h,pix,DPAD)
      const int hh = chl / HDIM, d0 = chl % HDIM;
      uint2 pk; pk.x = pk_rne(v0, v1); pk.y = pk_rne(v2, v3);
      *(uint2*)(Kb + (((size_t)b * NHEAD + hh) * NPIX + pix) * DPAD + d0) = pk;
    } else {                                           // V: (b,h,d,VSTR)
      const int ch2 = chl - DIMC;
      const int hh = ch2 / HDIM, d0 = ch2 % HDIM;
      short* o = Vb + (((size_t)b * NHEAD + hh) * HDIM + d0) * VSTR + pix;
      o[0] = f2bf(v0); o[VSTR] = f2bf(v1); o[2 * VSTR] = f2bf(v2); o[3 * VSTR] = f2bf(v3);
    }
  }
}

// ================= attention: one WAVE = 32 q-rows (2 tiles, 2 indep softmax chains) ====
// XCD pinning: h = blockIdx.x & 7 -> all blocks touching Bt[h] live on one XCD (L2-resident).
struct Chain { float m, sp; f32x4 O0, O1, O2; };

__device__ __forceinline__ void chain_init(Chain& c) {
  c.m = -1e30f; c.sp = 0.f;
  c.O0 = (f32x4){0.f,0.f,0.f,0.f}; c.O1 = c.O0; c.O2 = c.O0;
}

// full 32-col chunk step for one chain: bias+softmax+rescale+pack P into sPt[16][40]
__device__ __forceinline__ void chain_step(
    Chain& c, const f32x4 d0, const f32x4 d1, const uint2 bw0, const uint2 bw1,
    short* sPt, const int rr, const int qq)
{
  float s[8];
  s[0] = fmaf(d0[0], SC2, blo(bw0.x)); s[1] = fmaf(d0[1], SC2, bhi(bw0.x));
  s[2] = fmaf(d0[2], SC2, blo(bw0.y)); s[3] = fmaf(d0[3], SC2, bhi(bw0.y));
  s[4] = fmaf(d1[0], SC2, blo(bw1.x)); s[5] = fmaf(d1[1], SC2, bhi(bw1.x));
  s[6] = fmaf(d1[2], SC2, blo(bw1.y)); s[7] = fmaf(d1[3], SC2, bhi(bw1.y));
  float mx = s[0];
#pragma unroll
  for (int j = 1; j < 8; ++j) mx = fmaxf(mx, s[j]);
  mx = fmaxf(mx, __shfl_xor(mx, 16));
  mx = fmaxf(mx, __shfl_xor(mx, 32));
  const float mn = fmaxf(c.m, mx);
  const float al = exp2f(c.m - mn);
  c.m = mn;
  float p[8], ss = 0.f;
#pragma unroll
  for (int j = 0; j < 8; ++j) { p[j] = exp2f(s[j] - mn); ss += p[j]; }
  c.sp = fmaf(c.sp, al, ss);
  c.O0 *= al; c.O1 *= al; c.O2 *= al;
  uint2 w0; w0.x = pk_hu(p[0], p[1]); w0.y = pk_hu(p[2], p[3]);
  uint2 w1; w1.x = pk_hu(p[4], p[5]); w1.y = pk_hu(p[6], p[7]);
  *(uint2*)(sPt + rr * 40 + qq * 4) = w0;
  *(uint2*)(sPt + rr * 40 + 16 + qq * 4) = w1;
}

// tail chunk (16 cols): d1 half zeroed
__device__ __forceinline__ void chain_tail(
    Chain& c, const f32x4 d0, const uint2 bw0,
    short* sPt, const int rr, const int qq)
{
  float s[4];
  s[0] = fmaf(d0[0], SC2, blo(bw0.x)); s[1] = fmaf(d0[1], SC2, bhi(bw0.x));
  s[2] = fmaf(d0[2], SC2, blo(bw0.y)); s[3] = fmaf(d0[3], SC2, bhi(bw0.y));
  float mx = fmaxf(fmaxf(s[0], s[1]), fmaxf(s[2], s[3]));
  mx = fmaxf(mx, __shfl_xor(mx, 16));
  mx = fmaxf(mx, __shfl_xor(mx, 32));
  const float mn = fmaxf(c.m, mx);
  const float al = exp2f(c.m - mn);
  c.m = mn;
  float p[4], ss = 0.f;
#pragma unroll
  for (int j = 0; j < 4; ++j) { p[j] = exp2f(s[j] - mn); ss += p[j]; }
  c.sp = fmaf(c.sp, al, ss);
  c.O0 *= al; c.O1 *= al; c.O2 *= al;
  uint2 w0; w0.x = pk_hu(p[0], p[1]); w0.y = pk_hu(p[2], p[3]);
  *(uint2*)(sPt + rr * 40 + qq * 4) = w0;
  *(uint2*)(sPt + rr * 40 + 16 + qq * 4) = make_uint2(0, 0);
}

__global__ __launch_bounds__(256) void attn_kernel(
    const short* __restrict__ Q, const short* __restrict__ K,
    const short* __restrict__ V, const short* __restrict__ Bt,
    short* __restrict__ AO)
{
  __shared__ __align__(16) short sP[4][2][16 * 40];
  const int t = threadIdx.x;
  const int w = t >> 6, lane = t & 63;
  const int rr = lane & 15, qq = lane >> 4;
  const int x = blockIdx.x;            // 896 = 7*16*8
  const int h = x & 7;                 // XCD = x % 8 -> one head per XCD
  const int i = x >> 3;                // 0..111
  const int pb = i % 7, b = i / 7;     // 7 consecutive same-XCD blocks share (b,h)
  const int p = pb * 4 + w;            // q-tile pair 0..27
  if (p >= 25) return;
  const int qA = p * 32;
  const bool hasB = (qA + 16 < NPIX);
  const int qBr = hasB ? qA + 16 : qA;
  const int bh = b * NHEAD + h;

  const short* QpA = Q + ((size_t)bh * NPIX + qA + rr) * DPAD + qq * 8;
  const short* QpB = Q + ((size_t)bh * NPIX + qBr + rr) * DPAD + qq * 8;
  const bf16x8 qfA0 = *(const bf16x8*)QpA;
  const bf16x8 qfA1 = *(const bf16x8*)(QpA + 32);
  const bf16x8 qfB0 = *(const bf16x8*)QpB;
  const bf16x8 qfB1 = *(const bf16x8*)(QpB + 32);

  const short* Kp = K + ((size_t)bh * NPIX + rr) * DPAD + qq * 8;
  const short* Vp = V + (size_t)bh * HDIM * VSTR + qq * 8;
  const short* BpA = Bt + ((size_t)h * NPIX + qA + rr) * NPIX + qq * 4;
  const short* BpB = Bt + ((size_t)h * NPIX + qBr + rr) * NPIX + qq * 4;
  short* sPA = &sP[w][0][0];
  short* sPB = &sP[w][1][0];

  Chain cA, cB;
  chain_init(cA); chain_init(cB);

  for (int c = 0; c < 24; ++c) {
    const int m0 = c * 32;
    const short* kc = Kp + (size_t)m0 * DPAD;
    const bf16x8 ka0 = *(const bf16x8*)kc;
    const bf16x8 ka1 = *(const bf16x8*)(kc + 32);
    const bf16x8 kb0 = *(const bf16x8*)(kc + 16 * DPAD);
    const bf16x8 kb1 = *(const bf16x8*)(kc + 16 * DPAD + 32);

    f32x4 dA0 = (f32x4){0.f,0.f,0.f,0.f}, dA1 = dA0, dB0 = dA0, dB1 = dA0;
    dA0 = __builtin_amdgcn_mfma_f32_16x16x32_bf16(ka0, qfA0, dA0, 0, 0, 0);
    dA0 = __builtin_amdgcn_mfma_f32_16x16x32_bf16(ka1, qfA1, dA0, 0, 0, 0);
    dB0 = __builtin_amdgcn_mfma_f32_16x16x32_bf16(ka0, qfB0, dB0, 0, 0, 0);
    dB0 = __builtin_amdgcn_mfma_f32_16x16x32_bf16(ka1, qfB1, dB0, 0, 0, 0);
    dA1 = __builtin_amdgcn_mfma_f32_16x16x32_bf16(kb0, qfA0, dA1, 0, 0, 0);
    dA1 = __builtin_amdgcn_mfma_f32_16x16x32_bf16(kb1, qfA1, dA1, 0, 0, 0);
    dB1 = __builtin_amdgcn_mfma_f32_16x16x32_bf16(kb0, qfB0, dB1, 0, 0, 0);
    dB1 = __builtin_amdgcn_mfma_f32_16x16x32_bf16(kb1, qfB1, dB1, 0, 0, 0);

    const uint2 bwA0 = *(const uint2*)(BpA + m0);
    const uint2 bwA1 = *(const uint2*)(BpA + m0 + 16);
    const uint2 bwB0 = *(const uint2*)(BpB + m0);
    const uint2 bwB1 = *(const uint2*)(BpB + m0 + 16);

    chain_step(cA, dA0, dA1, bwA0, bwA1, sPA, rr, qq);
    chain_step(cB, dB0, dB1, bwB0, bwB1, sPB, rr, qq);

    const bf16x8 vf0 = *(const bf16x8*)(Vp + (size_t)rr * VSTR + m0);
    const bf16x8 vf1 = *(const bf16x8*)(Vp + (size_t)(16 + rr) * VSTR + m0);
    const bf16x8 vf2 = *(const bf16x8*)(Vp + (size_t)(32 + rr) * VSTR + m0);
    const bf16x8 pfA = *(const bf16x8*)(sPA + rr * 40 + qq * 8);
    const bf16x8 pfB = *(const bf16x8*)(sPB + rr * 40 + qq * 8);
    cA.O0 = __builtin_amdgcn_mfma_f32_16x16x32_bf16(vf0, pfA, cA.O0, 0, 0, 0);
    cA.O1 = __builtin_amdgcn_mfma_f32_16x16x32_bf16(vf1, pfA, cA.O1, 0, 0, 0);
    cA.O2 = __builtin_amdgcn_mfma_f32_16x16x32_bf16(vf2, pfA, cA.O2, 0, 0, 0);
    cB.O0 = __builtin_amdgcn_mfma_f32_16x16x32_bf16(vf0, pfB, cB.O0, 0, 0, 0);
    cB.O1 = __builtin_amdgcn_mfma_f32_16x16x32_bf16(vf1, pfB, cB.O1, 0, 0, 0);
    cB.O2 = __builtin_amdgcn_mfma_f32_16x16x32_bf16(vf2, pfB, cB.O2, 0, 0, 0);
  }

  { // ---- tail chunk: m in [768,784) ----
    const int m0 = 768;
    const short* kc = Kp + (size_t)m0 * DPAD;
    const bf16x8 ka0 = *(const bf16x8*)kc;
    const bf16x8 ka1 = *(const bf16x8*)(kc + 32);
    f32x4 dA0 = (f32x4){0.f,0.f,0.f,0.f}, dB0 = dA0;
    dA0 = __builtin_amdgcn_mfma_f32_16x16x32_bf16(ka0, qfA0, dA0, 0, 0, 0);
    dA0 = __builtin_amdgcn_mfma_f32_16x16x32_bf16(ka1, qfA1, dA0, 0, 0, 0);
    dB0 = __builtin_amdgcn_mfma_f32_16x16x32_bf16(ka0, qfB0, dB0, 0, 0, 0);
    dB0 = __builtin_amdgcn_mfma_f32_16x16x32_bf16(ka1, qfB1, dB0, 0, 0, 0);
    const uint2 bwA0 = *(const uint2*)(BpA + m0);
    const uint2 bwB0 = *(const uint2*)(BpB + m0);
    chain_tail(cA, dA0, bwA0, sPA, rr, qq);
    chain_tail(cB, dB0, bwB0, sPB, rr, qq);
    const bf16x8 vf0 = *(const bf16x8*)(Vp + (size_t)rr * VSTR + m0);
    const bf16x8 vf1 = *(const bf16x8*)(Vp + (size_t)(16 + rr) * VSTR + m0);
    const bf16x8 vf2 = *(const bf16x8*)(Vp + (size_t)(32 + rr) * VSTR + m0);
    const bf16x8 pfA = *(const bf16x8*)(sPA + rr * 40 + qq * 8);
    const bf16x8 pfB = *(const bf16x8*)(sPB + rr * 40 + qq * 8);
    cA.O0 = __builtin_amdgcn_mfma_f32_16x16x32_bf16(vf0, pfA, cA.O0, 0, 0, 0);
    cA.O1 = __builtin_amdgcn_mfma_f32_16x16x32_bf16(vf1, pfA, cA.O1, 0, 0, 0);
    cA.O2 = __builtin_amdgcn_mfma_f32_16x16x32_bf16(vf2, pfA, cA.O2, 0, 0, 0);
    cB.O0 = __builtin_amdgcn_mfma_f32_16x16x32_bf16(vf0, pfB, cB.O0, 0, 0, 0);
    cB.O1 = __builtin_amdgcn_mfma_f32_16x16x32_bf16(vf1, pfB, cB.O1, 0, 0, 0);
    cB.O2 = __builtin_amdgcn_mfma_f32_16x16x32_bf16(vf2, pfB, cB.O2, 0, 0, 0);
  }

  // ---- normalize + store AO (b, pix, 384) bf16 ----
  {
    float sA = cA.sp;
    sA += __shfl_xor(sA, 16); sA += __shfl_xor(sA, 32);
    const float invA = 1.f / sA;
    short* ao = AO + ((size_t)b * NPIX + qA + rr) * DIMC + h * HDIM + qq * 4;
    uint2 pk;
    pk.x = pk_rne(cA.O0[0] * invA, cA.O0[1] * invA);
    pk.y = pk_rne(cA.O0[2] * invA, cA.O0[3] * invA);
    *(uint2*)ao = pk;
    pk.x = pk_rne(cA.O1[0] * invA, cA.O1[1] * invA);
    pk.y = pk_rne(cA.O1[2] * invA, cA.O1[3] * invA);
    *(uint2*)(ao + 16) = pk;
    pk.x = pk_rne(cA.O2[0] * invA, cA.O2[1] * invA);
    pk.y = pk_rne(cA.O2[2] * invA, cA.O2[3] * invA);
    *(uint2*)(ao + 32) = pk;
  }
  if (hasB) {
    float sB2 = cB.sp;
    sB2 += __shfl_xor(sB2, 16); sB2 += __shfl_xor(sB2, 32);
    const float invB = 1.f / sB2;
    short* ao = AO + ((size_t)b * NPIX + qA + 16 + rr) * DIMC + h * HDIM + qq * 4;
    uint2 pk;
    pk.x = pk_rne(cB.O0[0] * invB, cB.O0[1] * invB);
    pk.y = pk_rne(cB.O0[2] * invB, cB.O0[3] * invB);
    *(uint2*)ao = pk;
    pk.x = pk_rne(cB.O1[0] * invB, cB.O1[1] * invB);
    pk.y = pk_rne(cB.O1[2] * invB, cB.O1[3] * invB);
    *(uint2*)(ao + 16) = pk;
    pk.x = pk_rne(cB.O2[0] * invB, cB.O2[1] * invB);
    pk.y = pk_rne(cB.O2[2] * invB, cB.O2[3] * invB);
    *(uint2*)(ao + 32) = pk;
  }
}

// ================= proj GEMM: out(b,c,pix) fp32 = Wp @ AO^T ==========
__global__ __launch_bounds__(256) void proj_gemm(
    const short* __restrict__ Wfp, const float* __restrict__ pb,
    const short* __restrict__ AO, float* __restrict__ out)
{
  const int t = threadIdx.x;
  const int w = t >> 6, lane = t & 63;
  const int rr = lane & 15, qq = lane >> 4;
  const int b = blockIdx.y;
  const int pix = blockIdx.x * 16 + rr;

  const short* Xp = AO + ((size_t)b * NPIX + pix) * DIMC + qq * 8;
  const short* wfp = Wfp + ((size_t)w * 12 * 64 + lane) * 8;

  f32x4 acc[6];
#pragma unroll
  for (int i = 0; i < 6; ++i) acc[i] = (f32x4){0.f, 0.f, 0.f, 0.f};

  for (int ks = 0; ks < 12; ++ks) {
    const bf16x8 xf = *(const bf16x8*)(Xp + ks * 32);
#pragma unroll
    for (int i = 0; i < 6; ++i) {
      const bf16x8 af = *(const bf16x8*)(wfp + (size_t)i * 24576 + ks * 512);
      acc[i] = __builtin_amdgcn_mfma_f32_16x16x32_bf16(af, xf, acc[i], 0, 0, 0);
    }
  }
#pragma unroll
  for (int i = 0; i < 6; ++i) {
    const int ch0 = (w + 4 * i) * 16 + qq * 4;
    const float4 bv = *(const float4*)(pb + ch0);
    float* o = out + ((size_t)b * DIMC + ch0) * NPIX + pix;
    o[0] = acc[i][0] + bv.x;
    o[NPIX] = acc[i][1] + bv.y;
    o[2 * NPIX] = acc[i][2] + bv.z;
    o[3 * NPIX] = acc[i][3] + bv.w;
  }
}

extern "C" void kernel_launch(void* const* d_in, const int* in_sizes, int n_in,
                              void* d_out, int out_size, void* d_ws, size_t ws_size,
                              hipStream_t stream)
{
  const float* ll     = (const float*)d_in[0];
  const float* ha     = (const float*)d_in[1];
  const float* q_w    = (const float*)d_in[2];
  const float* q_b    = (const float*)d_in[3];
  const float* kv_w   = (const float*)d_in[4];
  const float* kv_b   = (const float*)d_in[5];
  const float* proj_w = (const float*)d_in[6];
  const float* proj_b = (const float*)d_in[7];
  const float* biases = (const float*)d_in[8];
  // d_in[9] (bias_idxs) unused: index == |i1-i2|*28+|j1-j2| (validated R1/R2)
  float* out = (float*)d_out;

  short* Qb   = (short*)d_ws;                               // (b,h,784,64)
  short* Kb   = Qb   + (size_t)NB * NHEAD * NPIX * DPAD;    // (b,h,784,64)
  short* Vb   = Kb   + (size_t)NB * NHEAD * NPIX * DPAD;    // (b,h,48,800)
  short* Xll  = Vb   + (size_t)NB * NHEAD * HDIM * VSTR;    // (b,784,384)
  short* Xha  = Xll  + (size_t)NB * NPIX * DIMC;
  short* AO   = Xha  + (size_t)NB * NPIX * DIMC;            // (b,784,384)
  short* Bt   = AO   + (size_t)NB * NPIX * DIMC;            // (8,784,784)
  short* Wfq  = Bt   + (size_t)NHEAD * NPIX * NPIX;
  short* Wfkv = Wfq  + (size_t)12 * 64 * 24 * 8;
  short* Wfp  = Wfkv + (size_t)12 * 64 * 48 * 8;

  prep_kernel<<<dim3(3960), 256, 0, stream>>>(ll, ha, q_w, kv_w, proj_w, biases,
                                              Xll, Xha, Wfq, Wfkv, Wfp, Bt, Qb, Kb);
  gemm_q<<<dim3(49, NB), 256, 0, stream>>>(Wfq, q_b, Xll, Qb);
  gemm_kv<<<dim3(49, NB), 256, 0, stream>>>(Wfkv, kv_b, Xha, Kb, Vb);
  attn_kernel<<<dim3(896), 256, 0, stream>>>(Qb, Kb, Vb, Bt, AO);
  proj_gemm<<<dim3(49, NB), 256, 0, stream>>>(Wfp, proj_b, AO, out);
}

// Round 6
// 268.189 us; speedup vs baseline: 1.3693x; 1.1793x over previous
//
#include <hip/hip_runtime.h>

#define RES    28
#define DIMC   384
#define NHEAD  8
#define HDIM   48
#define DPAD   64
#define NPIX   784
#define NB     16
#define VSTR   800
#define SC2    0.20823294f    // 48^-0.5 * log2(e)
#define LOG2E  1.44269504f

typedef short bf16x8 __attribute__((ext_vector_type(8)));
typedef float f32x4  __attribute__((ext_vector_type(4)));

__device__ __forceinline__ short f2bf(float x) {
  union { float f; unsigned u; } v; v.f = x;
  return (short)((v.u + 0x7FFFu + ((v.u >> 16) & 1u)) >> 16);   // RNE
}
__device__ __forceinline__ unsigned pk_rne(float a, float b) {
  union { float f; unsigned u; } x, y; x.f = a; y.f = b;
  return __builtin_amdgcn_perm(y.u + 0x7FFFu + ((y.u >> 16) & 1u),
                               x.u + 0x7FFFu + ((x.u >> 16) & 1u), 0x07060302u);
}
__device__ __forceinline__ unsigned pk_hu(float a, float b) {   // round-half-up, 3 ops
  union { float f; unsigned u; } x, y; x.f = a; y.f = b;
  return __builtin_amdgcn_perm(y.u + 0x8000u, x.u + 0x8000u, 0x07060302u);
}
__device__ __forceinline__ float blo(unsigned u) { union { unsigned u; float f; } v; v.u = u << 16; return v.f; }
__device__ __forceinline__ float bhi(unsigned u) { union { unsigned u; float f; } v; v.u = u & 0xFFFF0000u; return v.f; }

// ================= prep: transpose+cvt X, pack W frags, bias matrix, Q/K pad zero ==========
// blocks [0,2496): transpose  [2496,2784): pack  [2784,3176): bias  [3176,3960): pads
// Wf2 layout (qkv fused): [ct9][ks12][mt8][lane64][8]  (ch = ct*128+mt*16+(lane&15))
// Wfp layout (proj):      [mtile24][ks12][lane64][8]
__global__ __launch_bounds__(256) void prep_kernel(
    const float* __restrict__ ll, const float* __restrict__ ha,
    const float* __restrict__ qw, const float* __restrict__ kvw, const float* __restrict__ pw,
    const float* __restrict__ biases,
    short* __restrict__ Xll, short* __restrict__ Xha,
    short* __restrict__ Wf2, short* __restrict__ Wfp,
    short* __restrict__ Bt, short* __restrict__ Qb, short* __restrict__ Kb)
{
  __shared__ __align__(16) short sT[64][72];
  __shared__ float sB[NPIX];
  const int bid = blockIdx.x, t = threadIdx.x;

  if (bid < 2496) {               // ---- transpose (b,c,pix) f32 -> (b,pix,c) bf16 ----
    const int px = bid % 13, cb = (bid / 13) % 6, zz = bid / 78;
    const int which = zz >> 4, b = zz & 15;
    const float* X = (which ? ha : ll) + (size_t)b * DIMC * NPIX;
    short* T = (which ? Xha : Xll) + (size_t)b * NPIX * DIMC;
    const int c0 = cb * 64, p0 = px * 64;
    const int rrr = t >> 4, pc = (t & 15) * 4;
#pragma unroll
    for (int i = 0; i < 4; ++i) {
      const int c = rrr + 16 * i;
      if (p0 + pc < NPIX) {
        float4 v = *(const float4*)(X + (size_t)(c0 + c) * NPIX + p0 + pc);
        sT[pc + 0][c] = f2bf(v.x); sT[pc + 1][c] = f2bf(v.y);
        sT[pc + 2][c] = f2bf(v.z); sT[pc + 3][c] = f2bf(v.w);
      }
    }
    __syncthreads();
    const int pr = t >> 3, cc = (t & 7) * 8;
#pragma unroll
    for (int i = 0; i < 2; ++i) {
      const int p = pr + 32 * i;
      if (p0 + p < NPIX)
        *(bf16x8*)(T + (size_t)(p0 + p) * DIMC + c0 + cc) = *(const bf16x8*)&sT[p][cc];
    }
  } else if (bid < 2784) {        // ---- pack weights ----
    int gid = (bid - 2496) * 256 + t;
    if (gid < 55296) {            // Wf2: ((ct*12+ks)*8+mt)*64+lane
      const int lane = gid & 63;
      const int mt = (gid >> 6) & 7;
      const int ks = (gid >> 9) % 12;
      const int ct = gid / 6144;
      const int chg = ct * 128 + mt * 16 + (lane & 15);    // 0..1151
      const int k = ks * 32 + (lane >> 4) * 8;
      const float* src = (chg < DIMC ? qw + (size_t)chg * DIMC
                                     : kvw + (size_t)(chg - DIMC) * DIMC) + k;
      const float4 a = *(const float4*)src;
      const float4 b = *(const float4*)(src + 4);
      bf16x8 o;
      o[0] = f2bf(a.x); o[1] = f2bf(a.y); o[2] = f2bf(a.z); o[3] = f2bf(a.w);
      o[4] = f2bf(b.x); o[5] = f2bf(b.y); o[6] = f2bf(b.z); o[7] = f2bf(b.w);
      *(bf16x8*)(Wf2 + (size_t)gid * 8) = o;
    } else {                      // Wfp (unchanged layout for proj)
      const int g2 = gid - 55296;
      const int lane = g2 & 63;
      const int ks = (g2 >> 6) % 12;
      const int mtile = g2 / 768;
      const int row = mtile * 16 + (lane & 15);
      const int k = ks * 32 + (lane >> 4) * 8;
      const float* src = pw + (size_t)row * DIMC + k;
      const float4 a = *(const float4*)src;
      const float4 b = *(const float4*)(src + 4);
      bf16x8 o;
      o[0] = f2bf(a.x); o[1] = f2bf(a.y); o[2] = f2bf(a.z); o[3] = f2bf(a.w);
      o[4] = f2bf(b.x); o[5] = f2bf(b.y); o[6] = f2bf(b.z); o[7] = f2bf(b.w);
      *(bf16x8*)(Wfp + (size_t)g2 * 8) = o;
    }
  } else if (bid < 3176) {        // ---- bias matrix Bt[h][n][m] = bias*log2e, bf16 ----
    const int bb = bid - 2784;
    const int h = bb / 49, mt = bb % 49;
    for (int i = t; i < NPIX; i += 256) sB[i] = biases[h * NPIX + i] * LOG2E;
    __syncthreads();
    const int mrow = mt * 16 + (t >> 4);
    const int i2 = mrow / RES, j2 = mrow - i2 * RES;
    short* orow = Bt + ((size_t)h * NPIX + mrow) * NPIX;
    for (int n0 = (t & 15) * 4; n0 < NPIX; n0 += 64) {
      float v[4];
#pragma unroll
      for (int u = 0; u < 4; ++u) {
        const int n = n0 + u;
        const int i1 = n / RES, j1 = n - i1 * RES;
        int di = i1 - i2; di = di < 0 ? -di : di;
        int dj = j1 - j2; dj = dj < 0 ? -dj : dj;
        v[u] = sB[di * RES + dj];
      }
      uint2 pk; pk.x = pk_rne(v[0], v[1]); pk.y = pk_rne(v[2], v[3]);
      *(uint2*)(orow + n0) = pk;
    }
  } else {                        // ---- zero Q/K pad cols d in [48,64) ----
    const int pp = bid - 3176;
    short* buf = (pp >= 392) ? Kb : Qb;
    const size_t r = (size_t)(pp % 392) * 256 + t;
    short* p = buf + r * DPAD + HDIM;
    *(int4*)p = make_int4(0, 0, 0, 0);
    *(int4*)(p + 8) = make_int4(0, 0, 0, 0);
  }
}

// ================= fused QKV tiled GEMM: tile = 128 ch x 112 pix, A staged in LDS ==========
// grid (9 ctiles, 112 pixtiles); ct 0-2: Q (from Xll), 3-5: K, 6-8: V (from Xha).
// wave w owns mtiles {2w, 2w+1} x 7 pixgroups -> 14 f32x4 accs. BK=64, 6 steps.
__global__ __launch_bounds__(256) void qkv_tiled(
    const short* __restrict__ Wf2, const float* __restrict__ qb, const float* __restrict__ kvb,
    const short* __restrict__ Xll, const short* __restrict__ Xha,
    short* __restrict__ Qb, short* __restrict__ Kb, short* __restrict__ Vb)
{
  __shared__ __align__(16) short sM[15360];   // A-stage [0,8192) / V-transpose [0,15360)
  const int t = threadIdx.x;
  const int w = t >> 6, lane = t & 63;
  const int rr = lane & 15, qq = lane >> 4;
  const int ct = blockIdx.x;                  // 0..8
  const int pt = blockIdx.y;                  // 0..111
  const int b = pt / 7, pt7 = pt % 7;
  const int px0 = pt7 * 112;

  const short* Xsel = (ct < 3 ? Xll : Xha) + (size_t)b * NPIX * DIMC;
  const short* Bp[7];
#pragma unroll
  for (int pg = 0; pg < 7; ++pg)
    Bp[pg] = Xsel + (size_t)(px0 + pg * 16 + rr) * DIMC + qq * 8;

  const short* Aslice = Wf2 + (size_t)ct * 12 * 8 * 512;   // [ks][mt][lane][8]

  f32x4 acc[2][7];
#pragma unroll
  for (int mi = 0; mi < 2; ++mi)
#pragma unroll
    for (int pg = 0; pg < 7; ++pg) acc[mi][pg] = (f32x4){0.f, 0.f, 0.f, 0.f};

  for (int bk = 0; bk < 6; ++bk) {
    if (bk) __syncthreads();                  // previous reads done before restage
    {   // stage 2 ks-slices (16 KB, contiguous in Wf2) -> sM[0..8192)
      const short* g = Aslice + (size_t)(2 * bk) * 8 * 512;
      const int o = t * 8;
#pragma unroll
      for (int i = 0; i < 4; ++i)
        *(bf16x8*)&sM[o + i * 2048] = *(const bf16x8*)(g + o + i * 2048);
    }
    __syncthreads();
#pragma unroll
    for (int ksl = 0; ksl < 2; ++ksl) {
      const int ko = bk * 64 + ksl * 32;
      bf16x8 af[2];
      af[0] = *(const bf16x8*)&sM[(ksl * 8 + 2 * w) * 512 + lane * 8];
      af[1] = *(const bf16x8*)&sM[(ksl * 8 + 2 * w + 1) * 512 + lane * 8];
#pragma unroll
      for (int pg = 0; pg < 7; ++pg) {
        const bf16x8 bf = *(const bf16x8*)(Bp[pg] + ko);
        acc[0][pg] = __builtin_amdgcn_mfma_f32_16x16x32_bf16(af[0], bf, acc[0][pg], 0, 0, 0);
        acc[1][pg] = __builtin_amdgcn_mfma_f32_16x16x32_bf16(af[1], bf, acc[1][pg], 0, 0, 0);
      }
    }
  }

  if (ct < 6) {
    // ---- Q/K epilogue: ch = (ct%3)*128 + ml*16 + qq*4 -> (b,h,pix,DPAD) ----
    const float* bias = (ct < 3) ? qb : kvb;
    short* dst = (ct < 3) ? Qb : Kb;
#pragma unroll
    for (int mi = 0; mi < 2; ++mi) {
      const int ch = (ct % 3) * 128 + (2 * w + mi) * 16 + qq * 4;
      const float4 bv = *(const float4*)(bias + ch);
      const int hh = ch / HDIM, d0 = ch % HDIM;
#pragma unroll
      for (int pg = 0; pg < 7; ++pg) {
        const int px = px0 + pg * 16 + rr;
        uint2 pk;
        pk.x = pk_rne(acc[mi][pg][0] + bv.x, acc[mi][pg][1] + bv.y);
        pk.y = pk_rne(acc[mi][pg][2] + bv.z, acc[mi][pg][3] + bv.w);
        *(uint2*)(dst + (((size_t)b * NHEAD + hh) * NPIX + px) * DPAD + d0) = pk;
      }
    }
  } else {
    // ---- V epilogue: bias, transpose via LDS [ch128][pad 120], coalesced row stores ----
    __syncthreads();                          // all waves done with sM (staging)
#pragma unroll
    for (int mi = 0; mi < 2; ++mi) {
      const int chl = (2 * w + mi) * 16 + qq * 4;          // 0..127
      const int chv = (ct - 6) * 128 + chl;                // 0..383
      const float4 bv = *(const float4*)(kvb + DIMC + chv);
      const float bb[4] = {bv.x, bv.y, bv.z, bv.w};
#pragma unroll
      for (int pg = 0; pg < 7; ++pg) {
        const int px = pg * 16 + rr;
#pragma unroll
        for (int j = 0; j < 4; ++j)
          sM[(chl + j) * 120 + px] = f2bf(acc[mi][pg][j] + bb[j]);
      }
    }
    __syncthreads();
    const int r = t >> 1, half = t & 1;       // 128 rows x 2 halves of 56 px
    const int chv = (ct - 6) * 128 + r;
    const int hh = chv / HDIM, d = chv % HDIM;
    short* dst = Vb + (((size_t)b * NHEAD + hh) * HDIM + d) * VSTR + px0 + half * 56;
    const short* src = &sM[r * 120 + half * 56];
#pragma unroll
    for (int i = 0; i < 7; ++i)
      *(int4*)(dst + i * 8) = *(const int4*)(src + i * 8);
  }
}

// ================= attention: one WAVE = 32 q-rows (2 tiles, 2 indep softmax chains) ====
struct Chain { float m, sp; f32x4 O0, O1, O2; };

__device__ __forceinline__ void chain_init(Chain& c) {
  c.m = -1e30f; c.sp = 0.f;
  c.O0 = (f32x4){0.f,0.f,0.f,0.f}; c.O1 = c.O0; c.O2 = c.O0;
}

__device__ __forceinline__ void chain_step(
    Chain& c, const f32x4 d0, const f32x4 d1, const uint2 bw0, const uint2 bw1,
    short* sPt, const int rr, const int qq)
{
  float s[8];
  s[0] = fmaf(d0[0], SC2, blo(bw0.x)); s[1] = fmaf(d0[1], SC2, bhi(bw0.x));
  s[2] = fmaf(d0[2], SC2, blo(bw0.y)); s[3] = fmaf(d0[3], SC2, bhi(bw0.y));
  s[4] = fmaf(d1[0], SC2, blo(bw1.x)); s[5] = fmaf(d1[1], SC2, bhi(bw1.x));
  s[6] = fmaf(d1[2], SC2, blo(bw1.y)); s[7] = fmaf(d1[3], SC2, bhi(bw1.y));
  float mx = s[0];
#pragma unroll
  for (int j = 1; j < 8; ++j) mx = fmaxf(mx, s[j]);
  mx = fmaxf(mx, __shfl_xor(mx, 16));
  mx = fmaxf(mx, __shfl_xor(mx, 32));
  const float mn = fmaxf(c.m, mx);
  const float al = exp2f(c.m - mn);
  c.m = mn;
  float p[8], ss = 0.f;
#pragma unroll
  for (int j = 0; j < 8; ++j) { p[j] = exp2f(s[j] - mn); ss += p[j]; }
  c.sp = fmaf(c.sp, al, ss);
  c.O0 *= al; c.O1 *= al; c.O2 *= al;
  uint2 w0; w0.x = pk_hu(p[0], p[1]); w0.y = pk_hu(p[2], p[3]);
  uint2 w1; w1.x = pk_hu(p[4], p[5]); w1.y = pk_hu(p[6], p[7]);
  *(uint2*)(sPt + rr * 40 + qq * 4) = w0;
  *(uint2*)(sPt + rr * 40 + 16 + qq * 4) = w1;
}

__device__ __forceinline__ void chain_tail(
    Chain& c, const f32x4 d0, const uint2 bw0,
    short* sPt, const int rr, const int qq)
{
  float s[4];
  s[0] = fmaf(d0[0], SC2, blo(bw0.x)); s[1] = fmaf(d0[1], SC2, bhi(bw0.x));
  s[2] = fmaf(d0[2], SC2, blo(bw0.y)); s[3] = fmaf(d0[3], SC2, bhi(bw0.y));
  float mx = fmaxf(fmaxf(s[0], s[1]), fmaxf(s[2], s[3]));
  mx = fmaxf(mx, __shfl_xor(mx, 16));
  mx = fmaxf(mx, __shfl_xor(mx, 32));
  const float mn = fmaxf(c.m, mx);
  const float al = exp2f(c.m - mn);
  c.m = mn;
  float p[4], ss = 0.f;
#pragma unroll
  for (int j = 0; j < 4; ++j) { p[j] = exp2f(s[j] - mn); ss += p[j]; }
  c.sp = fmaf(c.sp, al, ss);
  c.O0 *= al; c.O1 *= al; c.O2 *= al;
  uint2 w0; w0.x = pk_hu(p[0], p[1]); w0.y = pk_hu(p[2], p[3]);
  *(uint2*)(sPt + rr * 40 + qq * 4) = w0;
  *(uint2*)(sPt + rr * 40 + 16 + qq * 4) = make_uint2(0, 0);
}

__global__ __launch_bounds__(256) void attn_kernel(
    const short* __restrict__ Q, const short* __restrict__ K,
    const short* __restrict__ V, const short* __restrict__ Bt,
    short* __restrict__ AO)
{
  __shared__ __align__(16) short sP[4][2][16 * 40];
  const int t = threadIdx.x;
  const int w = t >> 6, lane = t & 63;
  const int rr = lane & 15, qq = lane >> 4;
  const int x = blockIdx.x;            // 896 = 7*16*8
  const int h = x & 7;                 // XCD pin: one head per XCD
  const int i = x >> 3;
  const int pb = i % 7, b = i / 7;
  const int p = pb * 4 + w;
  if (p >= 25) return;
  const int qA = p * 32;
  const bool hasB = (qA + 16 < NPIX);
  const int qBr = hasB ? qA + 16 : qA;
  const int bh = b * NHEAD + h;

  const short* QpA = Q + ((size_t)bh * NPIX + qA + rr) * DPAD + qq * 8;
  const short* QpB = Q + ((size_t)bh * NPIX + qBr + rr) * DPAD + qq * 8;
  const bf16x8 qfA0 = *(const bf16x8*)QpA;
  const bf16x8 qfA1 = *(const bf16x8*)(QpA + 32);
  const bf16x8 qfB0 = *(const bf16x8*)QpB;
  const bf16x8 qfB1 = *(const bf16x8*)(QpB + 32);

  const short* Kp = K + ((size_t)bh * NPIX + rr) * DPAD + qq * 8;
  const short* Vp = V + (size_t)bh * HDIM * VSTR + qq * 8;
  const short* BpA = Bt + ((size_t)h * NPIX + qA + rr) * NPIX + qq * 4;
  const short* BpB = Bt + ((size_t)h * NPIX + qBr + rr) * NPIX + qq * 4;
  short* sPA = &sP[w][0][0];
  short* sPB = &sP[w][1][0];

  Chain cA, cB;
  chain_init(cA); chain_init(cB);

  for (int c = 0; c < 24; ++c) {
    const int m0 = c * 32;
    const short* kc = Kp + (size_t)m0 * DPAD;
    const bf16x8 ka0 = *(const bf16x8*)kc;
    const bf16x8 ka1 = *(const bf16x8*)(kc + 32);
    const bf16x8 kb0 = *(const bf16x8*)(kc + 16 * DPAD);
    const bf16x8 kb1 = *(const bf16x8*)(kc + 16 * DPAD + 32);

    f32x4 dA0 = (f32x4){0.f,0.f,0.f,0.f}, dA1 = dA0, dB0 = dA0, dB1 = dA0;
    dA0 = __builtin_amdgcn_mfma_f32_16x16x32_bf16(ka0, qfA0, dA0, 0, 0, 0);
    dA0 = __builtin_amdgcn_mfma_f32_16x16x32_bf16(ka1, qfA1, dA0, 0, 0, 0);
    dB0 = __builtin_amdgcn_mfma_f32_16x16x32_bf16(ka0, qfB0, dB0, 0, 0, 0);
    dB0 = __builtin_amdgcn_mfma_f32_16x16x32_bf16(ka1, qfB1, dB0, 0, 0, 0);
    dA1 = __builtin_amdgcn_mfma_f32_16x16x32_bf16(kb0, qfA0, dA1, 0, 0, 0);
    dA1 = __builtin_amdgcn_mfma_f32_16x16x32_bf16(kb1, qfA1, dA1, 0, 0, 0);
    dB1 = __builtin_amdgcn_mfma_f32_16x16x32_bf16(kb0, qfB0, dB1, 0, 0, 0);
    dB1 = __builtin_amdgcn_mfma_f32_16x16x32_bf16(kb1, qfB1, dB1, 0, 0, 0);

    const uint2 bwA0 = *(const uint2*)(BpA + m0);
    const uint2 bwA1 = *(const uint2*)(BpA + m0 + 16);
    const uint2 bwB0 = *(const uint2*)(BpB + m0);
    const uint2 bwB1 = *(const uint2*)(BpB + m0 + 16);

    chain_step(cA, dA0, dA1, bwA0, bwA1, sPA, rr, qq);
    chain_step(cB, dB0, dB1, bwB0, bwB1, sPB, rr, qq);

    const bf16x8 vf0 = *(const bf16x8*)(Vp + (size_t)rr * VSTR + m0);
    const bf16x8 vf1 = *(const bf16x8*)(Vp + (size_t)(16 + rr) * VSTR + m0);
    const bf16x8 vf2 = *(const bf16x8*)(Vp + (size_t)(32 + rr) * VSTR + m0);
    const bf16x8 pfA = *(const bf16x8*)(sPA + rr * 40 + qq * 8);
    const bf16x8 pfB = *(const bf16x8*)(sPB + rr * 40 + qq * 8);
    cA.O0 = __builtin_amdgcn_mfma_f32_16x16x32_bf16(vf0, pfA, cA.O0, 0, 0, 0);
    cA.O1 = __builtin_amdgcn_mfma_f32_16x16x32_bf16(vf1, pfA, cA.O1, 0, 0, 0);
    cA.O2 = __builtin_amdgcn_mfma_f32_16x16x32_bf16(vf2, pfA, cA.O2, 0, 0, 0);
    cB.O0 = __builtin_amdgcn_mfma_f32_16x16x32_bf16(vf0, pfB, cB.O0, 0, 0, 0);
    cB.O1 = __builtin_amdgcn_mfma_f32_16x16x32_bf16(vf1, pfB, cB.O1, 0, 0, 0);
    cB.O2 = __builtin_amdgcn_mfma_f32_16x16x32_bf16(vf2, pfB, cB.O2, 0, 0, 0);
  }

  { // ---- tail chunk: m in [768,784); P over [784,800) forced to 0 ----
    const int m0 = 768;
    const short* kc = Kp + (size_t)m0 * DPAD;
    const bf16x8 ka0 = *(const bf16x8*)kc;
    const bf16x8 ka1 = *(const bf16x8*)(kc + 32);
    f32x4 dA0 = (f32x4){0.f,0.f,0.f,0.f}, dB0 = dA0;
    dA0 = __builtin_amdgcn_mfma_f32_16x16x32_bf16(ka0, qfA0, dA0, 0, 0, 0);
    dA0 = __builtin_amdgcn_mfma_f32_16x16x32_bf16(ka1, qfA1, dA0, 0, 0, 0);
    dB0 = __builtin_amdgcn_mfma_f32_16x16x32_bf16(ka0, qfB0, dB0, 0, 0, 0);
    dB0 = __builtin_amdgcn_mfma_f32_16x16x32_bf16(ka1, qfB1, dB0, 0, 0, 0);
    const uint2 bwA0 = *(const uint2*)(BpA + m0);
    const uint2 bwB0 = *(const uint2*)(BpB + m0);
    chain_tail(cA, dA0, bwA0, sPA, rr, qq);
    chain_tail(cB, dB0, bwB0, sPB, rr, qq);
    const bf16x8 vf0 = *(const bf16x8*)(Vp + (size_t)rr * VSTR + m0);
    const bf16x8 vf1 = *(const bf16x8*)(Vp + (size_t)(16 + rr) * VSTR + m0);
    const bf16x8 vf2 = *(const bf16x8*)(Vp + (size_t)(32 + rr) * VSTR + m0);
    const bf16x8 pfA = *(const bf16x8*)(sPA + rr * 40 + qq * 8);
    const bf16x8 pfB = *(const bf16x8*)(sPB + rr * 40 + qq * 8);
    cA.O0 = __builtin_amdgcn_mfma_f32_16x16x32_bf16(vf0, pfA, cA.O0, 0, 0, 0);
    cA.O1 = __builtin_amdgcn_mfma_f32_16x16x32_bf16(vf1, pfA, cA.O1, 0, 0, 0);
    cA.O2 = __builtin_amdgcn_mfma_f32_16x16x32_bf16(vf2, pfA, cA.O2, 0, 0, 0);
    cB.O0 = __builtin_amdgcn_mfma_f32_16x16x32_bf16(vf0, pfB, cB.O0, 0, 0, 0);
    cB.O1 = __builtin_amdgcn_mfma_f32_16x16x32_bf16(vf1, pfB, cB.O1, 0, 0, 0);
    cB.O2 = __builtin_amdgcn_mfma_f32_16x16x32_bf16(vf2, pfB, cB.O2, 0, 0, 0);
  }

  {
    float sA = cA.sp;
    sA += __shfl_xor(sA, 16); sA += __shfl_xor(sA, 32);
    const float invA = 1.f / sA;
    short* ao = AO + ((size_t)b * NPIX + qA + rr) * DIMC + h * HDIM + qq * 4;
    uint2 pk;
    pk.x = pk_rne(cA.O0[0] * invA, cA.O0[1] * invA);
    pk.y = pk_rne(cA.O0[2] * invA, cA.O0[3] * invA);
    *(uint2*)ao = pk;
    pk.x = pk_rne(cA.O1[0] * invA, cA.O1[1] * invA);
    pk.y = pk_rne(cA.O1[2] * invA, cA.O1[3] * invA);
    *(uint2*)(ao + 16) = pk;
    pk.x = pk_rne(cA.O2[0] * invA, cA.O2[1] * invA);
    pk.y = pk_rne(cA.O2[2] * invA, cA.O2[3] * invA);
    *(uint2*)(ao + 32) = pk;
  }
  if (hasB) {
    float sB2 = cB.sp;
    sB2 += __shfl_xor(sB2, 16); sB2 += __shfl_xor(sB2, 32);
    const float invB = 1.f / sB2;
    short* ao = AO + ((size_t)b * NPIX + qA + 16 + rr) * DIMC + h * HDIM + qq * 4;
    uint2 pk;
    pk.x = pk_rne(cB.O0[0] * invB, cB.O0[1] * invB);
    pk.y = pk_rne(cB.O0[2] * invB, cB.O0[3] * invB);
    *(uint2*)ao = pk;
    pk.x = pk_rne(cB.O1[0] * invB, cB.O1[1] * invB);
    pk.y = pk_rne(cB.O1[2] * invB, cB.O1[3] * invB);
    *(uint2*)(ao + 16) = pk;
    pk.x = pk_rne(cB.O2[0] * invB, cB.O2[1] * invB);
    pk.y = pk_rne(cB.O2[2] * invB, cB.O2[3] * invB);
    *(uint2*)(ao + 32) = pk;
  }
}

// ================= proj GEMM: out(b,c,pix) fp32 = Wp @ AO^T ==========
__global__ __launch_bounds__(256) void proj_gemm(
    const short* __restrict__ Wfp, const float* __restrict__ pb,
    const short* __restrict__ AO, float* __restrict__ out)
{
  const int t = threadIdx.x;
  const int w = t >> 6, lane = t & 63;
  const int rr = lane & 15, qq = lane >> 4;
  const int b = blockIdx.y;
  const int pix = blockIdx.x * 16 + rr;

  const short* Xp = AO + ((size_t)b * NPIX + pix) * DIMC + qq * 8;
  const short* wfp = Wfp + ((size_t)w * 12 * 64 + lane) * 8;

  f32x4 acc[6];
#pragma unroll
  for (int i = 0; i < 6; ++i) acc[i] = (f32x4){0.f, 0.f, 0.f, 0.f};

  for (int ks = 0; ks < 12; ++ks) {
    const bf16x8 xf = *(const bf16x8*)(Xp + ks * 32);
#pragma unroll
    for (int i = 0; i < 6; ++i) {
      const bf16x8 af = *(const bf16x8*)(wfp + (size_t)i * 24576 + ks * 512);
      acc[i] = __builtin_amdgcn_mfma_f32_16x16x32_bf16(af, xf, acc[i], 0, 0, 0);
    }
  }
#pragma unroll
  for (int i = 0; i < 6; ++i) {
    const int ch0 = (w + 4 * i) * 16 + qq * 4;
    const float4 bv = *(const float4*)(pb + ch0);
    float* o = out + ((size_t)b * DIMC + ch0) * NPIX + pix;
    o[0] = acc[i][0] + bv.x;
    o[NPIX] = acc[i][1] + bv.y;
    o[2 * NPIX] = acc[i][2] + bv.z;
    o[3 * NPIX] = acc[i][3] + bv.w;
  }
}

extern "C" void kernel_launch(void* const* d_in, const int* in_sizes, int n_in,
                              void* d_out, int out_size, void* d_ws, size_t ws_size,
                              hipStream_t stream)
{
  const float* ll     = (const float*)d_in[0];
  const float* ha     = (const float*)d_in[1];
  const float* q_w    = (const float*)d_in[2];
  const float* q_b    = (const float*)d_in[3];
  const float* kv_w   = (const float*)d_in[4];
  const float* kv_b   = (const float*)d_in[5];
  const float* proj_w = (const float*)d_in[6];
  const float* proj_b = (const float*)d_in[7];
  const float* biases = (const float*)d_in[8];
  // d_in[9] (bias_idxs) unused: index == |i1-i2|*28+|j1-j2| (validated R1/R2)
  float* out = (float*)d_out;

  short* Qb   = (short*)d_ws;                               // (b,h,784,64)
  short* Kb   = Qb   + (size_t)NB * NHEAD * NPIX * DPAD;    // (b,h,784,64)
  short* Vb   = Kb   + (size_t)NB * NHEAD * NPIX * DPAD;    // (b,h,48,800)
  short* Xll  = Vb   + (size_t)NB * NHEAD * HDIM * VSTR;    // (b,784,384)
  short* Xha  = Xll  + (size_t)NB * NPIX * DIMC;
  short* AO   = Xha  + (size_t)NB * NPIX * DIMC;            // (b,784,384)
  short* Bt   = AO   + (size_t)NB * NPIX * DIMC;            // (8,784,784)
  short* Wf2  = Bt   + (size_t)NHEAD * NPIX * NPIX;         // 55296*8
  short* Wfp  = Wf2  + (size_t)55296 * 8;                   // 18432*8

  prep_kernel<<<dim3(3960), 256, 0, stream>>>(ll, ha, q_w, kv_w, proj_w, biases,
                                              Xll, Xha, Wf2, Wfp, Bt, Qb, Kb);
  qkv_tiled<<<dim3(9, 112), 256, 0, stream>>>(Wf2, q_b, kv_b, Xll, Xha, Qb, Kb, Vb);
  attn_kernel<<<dim3(896), 256, 0, stream>>>(Qb, Kb, Vb, Bt, AO);
  proj_gemm<<<dim3(49, NB), 256, 0, stream>>>(Wfp, proj_b, AO, out);
}